// Round 6
// baseline (3191.778 us; speedup 1.0000x reference)
//
#include <hip/hip_runtime.h>
#include <math.h>

#define N_NODES 20000
#define D_INN   512
#define DH      256
#define NCH     7
#define NE      320000
#define NE2     100000
#define NB      8192
#define H3      2304   // 512 + 7*256
#define MAXN    0.996f

typedef unsigned short u16;
typedef __attribute__((ext_vector_type(8))) short bf16x8;
typedef __attribute__((ext_vector_type(4))) float f32x4;

__device__ __forceinline__ u16 f2b(float f) {    // RNE f32 -> bf16 bits
    unsigned int x = __float_as_uint(f);
    unsigned int r = (x + 0x7fffu + ((x >> 16) & 1u)) >> 16;
    return (u16)r;
}
__device__ __forceinline__ float b2f(u16 u) {
    return __uint_as_float(((unsigned int)u) << 16);
}

__device__ __forceinline__ float artanh_f(float x) {
    x = fminf(fmaxf(x, -1.0f + 1e-7f), 1.0f - 1e-7f);
    return 0.5f * (log1pf(x) - log1pf(-x));
}

__device__ __forceinline__ float block_sum256(float v) {
    __shared__ float sred[4];
    #pragma unroll
    for (int off = 32; off > 0; off >>= 1) v += __shfl_down(v, off, 64);
    int lane = threadIdx.x & 63;
    int w = threadIdx.x >> 6;
    if (lane == 0) sred[w] = v;
    __syncthreads();
    float tot = sred[0] + sred[1] + sred[2] + sred[3];
    __syncthreads();
    return tot;
}

__global__ void k_zero(float* __restrict__ p, int n) {
    int i = blockIdx.x * 256 + threadIdx.x;
    if (i < n) p[i] = 0.0f;
}
__global__ void k_izero(int* __restrict__ p, int n) {
    int i = blockIdx.x * 256 + threadIdx.x;
    if (i < n) p[i] = 0;
}

__global__ void k_f2b(const float* __restrict__ s, u16* __restrict__ d, int n4) {
    int i = blockIdx.x * 256 + threadIdx.x;
    int stride = gridDim.x * 256;
    for (; i < n4; i += stride) {
        float4 v = ((const float4*)s)[i];
        unsigned int lo = (unsigned int)f2b(v.x) | ((unsigned int)f2b(v.y) << 16);
        unsigned int hi = (unsigned int)f2b(v.z) | ((unsigned int)f2b(v.w) << 16);
        uint2 o; o.x = lo; o.y = hi;
        ((uint2*)d)[i] = o;
    }
}

// ===== batched CSR build (blockIdx.y = channel-in-group) =====
__global__ void k_hist(const int* __restrict__ dst, int* __restrict__ cnt, int ne) {
    int z = blockIdx.y;
    dst += (size_t)z * ne;
    cnt += (size_t)z * N_NODES;
    int i = blockIdx.x * 256 + threadIdx.x;
    if (i < ne) atomicAdd(&cnt[dst[i]], 1);
}

__global__ void k_scan(const int* __restrict__ cnt, int* __restrict__ rowptr,
                       int* __restrict__ cursor) {
    int z = blockIdx.x;
    cnt += (size_t)z * N_NODES;
    rowptr += (size_t)z * (N_NODES + 1);
    cursor += (size_t)z * N_NODES;
    __shared__ int part[256];
    int t = threadIdx.x;
    const int CH = (N_NODES + 255) / 256;
    int beg = t * CH;
    int end = beg + CH; if (end > N_NODES) end = N_NODES;
    int s = 0;
    for (int i = beg; i < end; ++i) s += cnt[i];
    part[t] = s;
    __syncthreads();
    for (int off = 1; off < 256; off <<= 1) {
        int v = (t >= off) ? part[t - off] : 0;
        __syncthreads();
        part[t] += v;
        __syncthreads();
    }
    int run = (t == 0) ? 0 : part[t - 1];
    for (int i = beg; i < end; ++i) {
        rowptr[i] = run; cursor[i] = run; run += cnt[i];
    }
    if (t == 255) rowptr[N_NODES] = part[255];
}

__global__ void k_place_sv(const int* __restrict__ src, const int* __restrict__ dst,
                           const float* __restrict__ val, int* __restrict__ cursor,
                           int* __restrict__ psrc, float* __restrict__ pval, int ne) {
    int z = blockIdx.y;
    src += (size_t)z * ne; dst += (size_t)z * ne; val += (size_t)z * ne;
    cursor += (size_t)z * N_NODES; psrc += (size_t)z * ne; pval += (size_t)z * ne;
    int i = blockIdx.x * 256 + threadIdx.x;
    if (i < ne) {
        int d = dst[i];
        int pos = atomicAdd(&cursor[d], 1);
        psrc[pos] = src[i];
        pval[pos] = val[i];
    }
}

__global__ void k_place_s(const int* __restrict__ src, const int* __restrict__ dst,
                          int* __restrict__ cursor, int* __restrict__ psrc, int ne) {
    int z = blockIdx.y;
    src += (size_t)z * ne; dst += (size_t)z * ne;
    cursor += (size_t)z * N_NODES; psrc += (size_t)z * ne;
    int i = blockIdx.x * 256 + threadIdx.x;
    if (i < ne) {
        int d = dst[i];
        int pos = atomicAdd(&cursor[d], 1);
        psrc[pos] = src[i];
    }
}

// x_hyp = proj(expmap0(f1)) -> bf16; clamped row norm -> xhn (f32)
__global__ void k_expmap_proj_in(const float* __restrict__ f1,
                                 u16* __restrict__ xhyp, float* __restrict__ xhn) {
    int r = blockIdx.x, t = threadIdx.x;
    const float* u = f1 + (size_t)r * D_INN;
    float v0 = u[t], v1 = u[t + 256];
    float ss = block_sum256(v0 * v0 + v1 * v1);
    float nraw = sqrtf(ss);
    float n = fmaxf(nraw, 1e-15f);
    float c = tanhf(n) / n;
    float ny = c * nraw;
    float np = fmaxf(ny, 1e-15f);
    float s = (np > MAXN) ? MAXN / np : 1.0f;
    float cs = c * s;
    u16* o = xhyp + (size_t)r * D_INN;
    o[t] = f2b(cs * v0);
    o[t + 256] = f2b(cs * v1);
    if (t == 0) xhn[r] = fminf(np, MAXN);
}

__global__ void k_hb(const float* __restrict__ b_hyp,
                     float* __restrict__ hb, float* __restrict__ hb2) {
    int i = blockIdx.x, t = threadIdx.x;
    float v = b_hyp[i * DH + t];
    float ss = block_sum256(v * v);
    float nraw = sqrtf(ss);
    float n = fmaxf(nraw, 1e-15f);
    float c = tanhf(n) / n;
    float ny = c * nraw;
    float np = fmaxf(ny, 1e-15f);
    float s = (np > MAXN) ? MAXN / np : 1.0f;
    float hv = c * s * v;
    hb[i * DH + t] = hv;
    float s2 = block_sum256(hv * hv);
    if (t == 0) hb2[i] = s2;
}

// batched; in-place bf16 row: mobius finalize->proj->mobius_add->proj->logmap0
__global__ void k_rowfuse1(u16* __restrict__ T, const float* __restrict__ xhn,
                           const float* __restrict__ hb, const float* __restrict__ hb2) {
    int z = blockIdx.y;
    u16* row = T + ((size_t)z * N_NODES + blockIdx.x) * DH;
    hb += (size_t)z * DH;
    int t = threadIdx.x;
    float m = b2f(row[t]);
    float ss = block_sum256(m * m);
    float mxn_raw = sqrtf(ss);
    float mxn = fmaxf(mxn_raw, 1e-15f);
    float xn = xhn[blockIdx.x];
    float tt = tanhf(mxn / xn * artanh_f(xn));
    float coef = tt / mxn;
    float res = coef * m;
    float nres = coef * mxn_raw;
    float np = fmaxf(nres, 1e-15f);
    float s1 = (np > MAXN) ? MAXN / np : 1.0f;
    res *= s1;
    float n1 = fminf(np, MAXN);
    float hbv = hb[t];
    float xy = block_sum256(res * hbv);
    float x2 = n1 * n1, y2 = hb2[z];
    float num = (1.0f + 2.0f * xy + y2) * res + (1.0f - x2) * hbv;
    float den = fmaxf(1.0f + 2.0f * xy + x2 * y2, 1e-15f);
    float o = num / den;
    float no2 = block_sum256(o * o);
    float nop = fmaxf(sqrtf(no2), 1e-15f);
    float s2 = (nop > MAXN) ? MAXN / nop : 1.0f;
    float p = o * s2;
    float n2 = fminf(nop, MAXN);
    row[t] = f2b(artanh_f(n2) / n2 * p);
}

// batched CSR gather (wave-split edges, uint2-vectorized features) + fused
// rowfuse2 hyperbolic chain -> bf16 out.
// Wave w handles edges beg+w, beg+w+4, ...; lane covers features lane*4..+3.
__global__ void k_gather_fuse2(const int* __restrict__ rowptr, const int* __restrict__ psrc,
                               const float* __restrict__ pval, const u16* __restrict__ xt,
                               u16* __restrict__ out) {
    int z = blockIdx.y;
    rowptr += (size_t)z * (N_NODES + 1);
    psrc += (size_t)z * NE;
    pval += (size_t)z * NE;
    xt += (size_t)z * N_NODES * DH;
    out += (size_t)z * N_NODES * DH;
    __shared__ int ssrc[256];
    __shared__ float sval[256];
    __shared__ float red[4][256];
    int n = blockIdx.x, t = threadIdx.x;
    int w = t >> 6, lane = t & 63;
    int beg = rowptr[n], end = rowptr[n + 1];
    float a0 = 0.f, a1 = 0.f, a2 = 0.f, a3 = 0.f;
    for (int base = beg; base < end; base += 256) {
        int cnt = end - base; if (cnt > 256) cnt = 256;
        __syncthreads();
        if (t < cnt) { ssrc[t] = psrc[base + t]; sval[t] = pval[base + t]; }
        __syncthreads();
        for (int i = w; i < cnt; i += 4) {
            float v = sval[i];
            uint2 u = *(const uint2*)(xt + (size_t)ssrc[i] * DH + lane * 4);
            a0 = fmaf(v, __uint_as_float(u.x << 16), a0);
            a1 = fmaf(v, __uint_as_float(u.x & 0xffff0000u), a1);
            a2 = fmaf(v, __uint_as_float(u.y << 16), a2);
            a3 = fmaf(v, __uint_as_float(u.y & 0xffff0000u), a3);
        }
    }
    __syncthreads();
    red[w][lane * 4 + 0] = a0;
    red[w][lane * 4 + 1] = a1;
    red[w][lane * 4 + 2] = a2;
    red[w][lane * 4 + 3] = a3;
    __syncthreads();
    float acc = red[0][t] + red[1][t] + red[2][t] + red[3][t];
    // rowfuse2: expmap0->proj->logmap0->relu->expmap0->proj->logmap0
    float ss = block_sum256(acc * acc);
    float nraw = sqrtf(ss);
    float n_ = fmaxf(nraw, 1e-15f);
    float c1 = tanhf(n_) / n_;
    float h = c1 * acc;
    float nh = c1 * nraw;
    float np1 = fmaxf(nh, 1e-15f);
    float s1 = (np1 > MAXN) ? MAXN / np1 : 1.0f;
    h *= s1;
    float n1 = fminf(np1, MAXN);
    float u = artanh_f(n1) / n1 * h;
    u = fmaxf(u, 0.0f);
    float ss2 = block_sum256(u * u);
    float n2raw = sqrtf(ss2);
    float n2 = fmaxf(n2raw, 1e-15f);
    float c3 = tanhf(n2) / n2;
    float e = c3 * u;
    float ne = c3 * n2raw;
    float np3 = fmaxf(ne, 1e-15f);
    float s3 = (np3 > MAXN) ? MAXN / np3 : 1.0f;
    e *= s3;
    float n3 = fminf(np3, MAXN);
    out[(size_t)n * DH + t] = f2b(artanh_f(n3) / n3 * e);
}

// batched: agg[n] = d[n] + sum_in d[src]; wave-split, vectorized; bf16 in/out
__global__ void k_gather_add(const int* __restrict__ rowptr, const int* __restrict__ psrc,
                             const u16* __restrict__ d, u16* __restrict__ out) {
    int z = blockIdx.y;
    rowptr += (size_t)z * (N_NODES + 1);
    psrc += (size_t)z * NE;
    d += (size_t)z * N_NODES * DH;
    out += (size_t)z * N_NODES * DH;
    __shared__ int ssrc[256];
    __shared__ float red[4][256];
    int n = blockIdx.x, t = threadIdx.x;
    int w = t >> 6, lane = t & 63;
    int beg = rowptr[n], end = rowptr[n + 1];
    float a0 = 0.f, a1 = 0.f, a2 = 0.f, a3 = 0.f;
    for (int base = beg; base < end; base += 256) {
        int cnt = end - base; if (cnt > 256) cnt = 256;
        __syncthreads();
        if (t < cnt) ssrc[t] = psrc[base + t];
        __syncthreads();
        for (int i = w; i < cnt; i += 4) {
            uint2 u = *(const uint2*)(d + (size_t)ssrc[i] * DH + lane * 4);
            a0 += __uint_as_float(u.x << 16);
            a1 += __uint_as_float(u.x & 0xffff0000u);
            a2 += __uint_as_float(u.y << 16);
            a3 += __uint_as_float(u.y & 0xffff0000u);
        }
    }
    __syncthreads();
    red[w][lane * 4 + 0] = a0;
    red[w][lane * 4 + 1] = a1;
    red[w][lane * 4 + 2] = a2;
    red[w][lane * 4 + 3] = a3;
    __syncthreads();
    float acc = red[0][t] + red[1][t] + red[2][t] + red[3][t] + b2f(d[(size_t)n * DH + t]);
    out[(size_t)n * DH + t] = f2b(acc);
}

// batched column stats from bf16
__global__ void k_colstats(const u16* __restrict__ zp,
                           float* __restrict__ csum, float* __restrict__ csq) {
    int z = blockIdx.y;
    zp += (size_t)z * N_NODES * DH;
    csum += (size_t)z * DH;
    csq += (size_t)z * DH;
    int t = threadIdx.x;
    int r0 = blockIdx.x * 100;
    float s = 0.0f, q = 0.0f;
    for (int r = r0; r < r0 + 100; ++r) {
        float v = b2f(zp[(size_t)r * DH + t]);
        s += v;
        q += v * v;
    }
    atomicAdd(&csum[t], s);
    atomicAdd(&csq[t], q);
}

// batched batchnorm + tanh, in-place bf16
__global__ void k_normtanh(u16* __restrict__ zp, const float* __restrict__ csum,
                           const float* __restrict__ csq, const float* __restrict__ gamma,
                           const float* __restrict__ beta) {
    int z = blockIdx.y;
    u16* row = zp + ((size_t)z * N_NODES + blockIdx.x) * DH;
    csum += (size_t)z * DH; csq += (size_t)z * DH;
    gamma += (size_t)z * DH; beta += (size_t)z * DH;
    int j = threadIdx.x;
    float mu = csum[j] * (1.0f / N_NODES);
    float var = csq[j] * (1.0f / N_NODES) - mu * mu;
    float inv = 1.0f / sqrtf(var + 1e-5f);
    float v = (b2f(row[j]) - mu) * inv * gamma[j] + beta[j];
    row[j] = f2b(tanhf(v));
}

// f1 slice of S,P (cols 0..511)
__global__ void k_pair0(const int* __restrict__ ei, const int* __restrict__ eid,
                        const float* __restrict__ f1, u16* __restrict__ S,
                        u16* __restrict__ P) {
    int b = blockIdx.x, t = threadIdx.x;
    int e = eid[b];
    int n0 = ei[e], n1 = ei[NE2 + e];
    const float* xa = f1 + (size_t)n0 * D_INN;
    const float* xb = f1 + (size_t)n1 * D_INN;
    u16* so = S + (size_t)b * H3;
    u16* po = P + (size_t)b * H3;
    for (int j = t; j < D_INN; j += 256) {
        float a = xa[j], c = xb[j];
        so[j] = f2b(a + c);
        po[j] = f2b(a * c);
    }
}

// batched channel slice of S,P gathered from z_ch (bf16)
__global__ void k_gather_ch(const int* __restrict__ ei, const int* __restrict__ eid,
                            const u16* __restrict__ zch, u16* __restrict__ S,
                            u16* __restrict__ P, int col0base) {
    int z = blockIdx.y;
    const u16* zp = zch + (size_t)z * N_NODES * DH;
    int col0 = col0base + z * DH;
    int b = blockIdx.x, j = threadIdx.x;
    int e = eid[b];
    int n0 = ei[e], n1 = ei[NE2 + e];
    float a = b2f(zp[(size_t)n0 * DH + j]);
    float c = b2f(zp[(size_t)n1 * DH + j]);
    S[(size_t)b * H3 + col0 + j] = f2b(a + c);
    P[(size_t)b * H3 + col0 + j] = f2b(a * c);
}

__global__ void k_final(const float* __restrict__ h2, const float* __restrict__ Wf3,
                        const float* __restrict__ bf3, float* __restrict__ out) {
    int r = blockIdx.x, t = threadIdx.x;
    const float* hr = h2 + (size_t)r * 576;
    float acc[7] = {0, 0, 0, 0, 0, 0, 0};
    for (int cb = t; cb < 576; cb += 64) {
        float h = hr[cb];
        #pragma unroll
        for (int o = 0; o < 7; ++o) acc[o] = fmaf(h, Wf3[o * 576 + cb], acc[o]);
    }
    #pragma unroll
    for (int o = 0; o < 7; ++o) {
        #pragma unroll
        for (int off = 32; off > 0; off >>= 1) acc[o] += __shfl_down(acc[o], off, 64);
    }
    if (t == 0) {
        #pragma unroll
        for (int o = 0; o < 7; ++o) out[(size_t)r * 7 + o] = acc[o] + bf3[o];
    }
}

// ===== bf16 MFMA GEMM (batched over blockIdx.z with strides).
// C[z][M,N] = A[z][M,K] @ W[z][N,K]^T + bias[z]; 128x128 tile, BK=32, 4 waves.
// Staging via global_load_lds width-16: wave w stages 16-row group g=w+4p,
// lane l -> row g*16+(l&15), k-chunk (l>>4); LDS dest = wave-uniform base
// + lane*16B (linear fragment order). Fragment ds_read_b128 at +lane*16B is
// contiguous -> conflict-free. No LDS write instructions at all.
// EP: 2=sigmoid->bf16, 3=relu->bf16, 4=aux*relu->bf16, 5=bf16, 6=relu->f32
template <int EP>
__global__ __launch_bounds__(256, 2) void k_gemm_mfma(
    const u16* __restrict__ A, const u16* __restrict__ W,
    const float* __restrict__ bias, void* __restrict__ outv,
    const u16* __restrict__ aux, int M, int N, int K,
    size_t sA, size_t sW, size_t sC, int sBias) {
    __shared__ short As[4096];   // 128x32 bf16, fragment order
    __shared__ short Ws[4096];
    const int z = blockIdx.z;
    A += (size_t)z * sA;
    W += (size_t)z * sW;
    const size_t zC = (size_t)z * sC;
    const int t = threadIdx.x;
    const int lane = t & 63;
    const int w = t >> 6;
    const int wr = w >> 1, wc = w & 1;
    const int row0 = blockIdx.y * 128, col0 = blockIdx.x * 128;
    const int rr = lane & 15, kc = lane >> 4;
    // per-wave staging source rows (clamped)
    int gr[2], gc[2];
    #pragma unroll
    for (int p = 0; p < 2; ++p) {
        int r = (w + p * 4) * 16 + rr;
        gr[p] = row0 + r; if (gr[p] >= M) gr[p] = M - 1;
        gc[p] = col0 + r; if (gc[p] >= N) gc[p] = N - 1;
    }
    f32x4 acc[4][4] = {};
    for (int k0 = 0; k0 < K; k0 += 32) {
        #pragma unroll
        for (int p = 0; p < 2; ++p) {
            int g = w + p * 4;
            __builtin_amdgcn_global_load_lds(
                (const __attribute__((address_space(1))) unsigned int*)(A + (size_t)gr[p] * K + k0 + kc * 8),
                (__attribute__((address_space(3))) unsigned int*)(As + g * 512), 16, 0, 0);
            __builtin_amdgcn_global_load_lds(
                (const __attribute__((address_space(1))) unsigned int*)(W + (size_t)gc[p] * K + k0 + kc * 8),
                (__attribute__((address_space(3))) unsigned int*)(Ws + g * 512), 16, 0, 0);
        }
        __syncthreads();
        bf16x8 af[4], bfr[4];
        #pragma unroll
        for (int m = 0; m < 4; ++m)
            af[m] = *(const bf16x8*)(As + (wr * 4 + m) * 512 + lane * 8);
        #pragma unroll
        for (int n = 0; n < 4; ++n)
            bfr[n] = *(const bf16x8*)(Ws + (wc * 4 + n) * 512 + lane * 8);
        #pragma unroll
        for (int m = 0; m < 4; ++m)
            #pragma unroll
            for (int n = 0; n < 4; ++n)
                acc[m][n] = __builtin_amdgcn_mfma_f32_16x16x32_bf16(af[m], bfr[n], acc[m][n], 0, 0, 0);
        __syncthreads();
    }
    const int cl = lane & 15, rh = (lane >> 4) * 4;
    #pragma unroll
    for (int m = 0; m < 4; ++m) {
        #pragma unroll
        for (int n = 0; n < 4; ++n) {
            int col = col0 + wc * 64 + n * 16 + cl;
            if (col >= N) continue;
            float bv = bias ? bias[z * sBias + col] : 0.0f;
            #pragma unroll
            for (int r = 0; r < 4; ++r) {
                int row = row0 + wr * 64 + m * 16 + rh + r;
                if (row >= M) continue;
                float v = acc[m][n][r] + bv;
                size_t idx = zC + (size_t)row * N + col;
                if (EP == 2) ((u16*)outv)[idx] = f2b(1.0f / (1.0f + expf(-v)));
                if (EP == 3) ((u16*)outv)[idx] = f2b(fmaxf(v, 0.0f));
                if (EP == 4) { float g = b2f(aux[idx]); ((u16*)outv)[idx] = f2b(g * fmaxf(v, 0.0f)); }
                if (EP == 5) ((u16*)outv)[idx] = f2b(v);
                if (EP == 6) ((float*)outv)[idx] = fmaxf(v, 0.0f);
            }
        }
    }
}

static inline void gemm_b(int ep, const u16* A, const u16* W, const float* bias, void* out,
                          const u16* aux, int M, int N, int K, int Z,
                          size_t sA, size_t sW, size_t sC, int sBias, hipStream_t st) {
    dim3 g((N + 127) / 128, (M + 127) / 128, Z);
    switch (ep) {
        case 2: k_gemm_mfma<2><<<g, 256, 0, st>>>(A, W, bias, out, aux, M, N, K, sA, sW, sC, sBias); break;
        case 3: k_gemm_mfma<3><<<g, 256, 0, st>>>(A, W, bias, out, aux, M, N, K, sA, sW, sC, sBias); break;
        case 4: k_gemm_mfma<4><<<g, 256, 0, st>>>(A, W, bias, out, aux, M, N, K, sA, sW, sC, sBias); break;
        case 5: k_gemm_mfma<5><<<g, 256, 0, st>>>(A, W, bias, out, aux, M, N, K, sA, sW, sC, sBias); break;
        case 6: k_gemm_mfma<6><<<g, 256, 0, st>>>(A, W, bias, out, aux, M, N, K, sA, sW, sC, sBias); break;
    }
}

static inline void conv_w(const float* s, u16* d, size_t n, hipStream_t st) {
    int n4 = (int)(n / 4);
    int grid = (n4 + 255) / 256;
    if (grid > 2048) grid = 2048;
    k_f2b<<<grid, 256, 0, st>>>(s, d, n4);
}

extern "C" void kernel_launch(void* const* d_in, const int* in_sizes, int n_in, void* d_out,
                              int out_size, void* d_ws, size_t ws_size, hipStream_t stream) {
    const float* f1 = (const float*)d_in[0];
    const int* adj_src = (const int*)d_in[1];
    const int* adj_dst = (const int*)d_in[2];
    const float* adj_val = (const float*)d_in[3];
    const int* edge_src = (const int*)d_in[4];
    const int* edge_dst = (const int*)d_in[5];
    const int* edge_index = (const int*)d_in[6];
    const int* edge_id = (const int*)d_in[7];
    const float* W_hyp = (const float*)d_in[8];
    const float* b_hyp = (const float*)d_in[9];
    const float* Wd = (const float*)d_in[10];
    const float* bd = (const float*)d_in[11];
    const float* Wg1 = (const float*)d_in[12];
    const float* bg1 = (const float*)d_in[13];
    const float* gamma = (const float*)d_in[14];
    const float* beta = (const float*)d_in[15];
    const float* Wg2 = (const float*)d_in[16];
    const float* bg2 = (const float*)d_in[17];
    const float* Wgate = (const float*)d_in[18];
    const float* bgate = (const float*)d_in[19];
    const float* Wint = (const float*)d_in[20];
    const float* bint = (const float*)d_in[21];
    const float* Wout = (const float*)d_in[22];
    const float* bout = (const float*)d_in[23];
    const float* Wf1 = (const float*)d_in[24];
    const float* bf1 = (const float*)d_in[25];
    const float* Wf2 = (const float*)d_in[26];
    const float* bf2 = (const float*)d_in[27];
    const float* Wf3 = (const float*)d_in[28];
    const float* bf3 = (const float*)d_in[29];
    float* outp = (float*)d_out;

    // ---- workspace bump allocator (~245 MB) ----
    char* base = (char*)d_ws;
    size_t off = 0;
    auto alloc = [&](size_t bytes) -> char* {
        char* p = base + off;
        off += (bytes + 255) & ~(size_t)255;
        return p;
    };
    u16* Whyp_b = (u16*)alloc((size_t)NCH * DH * D_INN * 2);
    u16* Wd_b   = (u16*)alloc((size_t)NCH * DH * DH * 2);
    u16* Wg1_b  = (u16*)alloc((size_t)NCH * DH * DH * 2);
    u16* Wg2_b  = (u16*)alloc((size_t)NCH * DH * DH * 2);
    u16* Wgate_b = (u16*)alloc((size_t)H3 * H3 * 2);
    u16* Wint_b  = (u16*)alloc((size_t)H3 * H3 * 2);
    u16* Wout_b  = (u16*)alloc((size_t)H3 * H3 * 2);
    u16* Wf1_b   = (u16*)alloc((size_t)1152 * H3 * 2);
    u16* Wf2_b   = (u16*)alloc((size_t)576 * 1152 * 2);
    u16* S_b = (u16*)alloc((size_t)NB * H3 * 2);
    u16* P_b = (u16*)alloc((size_t)NB * H3 * 2);
    const size_t NDB = (size_t)N_NODES * DH;       // per-channel elems
    u16* buf1 = (u16*)alloc(4 * NDB * 2);          // group ping
    u16* buf2 = (u16*)alloc(4 * NDB * 2);          // group pong
    u16* xhyp_b = (u16*)alloc((size_t)N_NODES * D_INN * 2);
    // batched CSR scratch (max group = 4 channels)
    int* cnt = (int*)alloc(4 * (size_t)N_NODES * 4);
    int* cursor = (int*)alloc(4 * (size_t)N_NODES * 4);
    int* rowptrA = (int*)alloc(4 * (size_t)(N_NODES + 1) * 4);
    int* rowptrE = (int*)alloc(4 * (size_t)(N_NODES + 1) * 4);
    int* psrcA = (int*)alloc(4 * (size_t)NE * 4);
    float* pvalA = (float*)alloc(4 * (size_t)NE * 4);
    int* psrcE = (int*)alloc(4 * (size_t)NE * 4);
    float* xhn = (float*)alloc((size_t)N_NODES * 4);
    float* hb = (float*)alloc((size_t)NCH * DH * 4);
    float* hb2 = (float*)alloc(NCH * 4);
    float* csum = (float*)alloc((size_t)4 * DH * 4);
    float* csq = (float*)alloc((size_t)4 * DH * 4);
    // stage-C overlays (GNN buffers dead by then)
    u16* G_b = buf1;                 // 37.75 MB <= 40.96
    float* h2f = (float*)buf2;       // 18.87 MB <= 40.96

    const int EG = (NE + 255) / 256;

    conv_w(W_hyp, Whyp_b, (size_t)NCH * DH * D_INN, stream);
    conv_w(Wd, Wd_b, (size_t)NCH * DH * DH, stream);
    conv_w(Wg1, Wg1_b, (size_t)NCH * DH * DH, stream);
    conv_w(Wg2, Wg2_b, (size_t)NCH * DH * DH, stream);
    conv_w(Wgate, Wgate_b, (size_t)H3 * H3, stream);
    conv_w(Wint, Wint_b, (size_t)H3 * H3, stream);
    conv_w(Wout, Wout_b, (size_t)H3 * H3, stream);
    conv_w(Wf1, Wf1_b, (size_t)1152 * H3, stream);
    conv_w(Wf2, Wf2_b, (size_t)576 * 1152, stream);

    k_expmap_proj_in<<<N_NODES, 256, 0, stream>>>(f1, xhyp_b, xhn);
    k_hb<<<NCH, 256, 0, stream>>>(b_hyp, hb, hb2);
    k_pair0<<<NB, 256, 0, stream>>>(edge_index, edge_id, f1, S_b, P_b);

    const int g0s[2] = {0, 4};
    const int gns[2] = {4, 3};
    for (int gi = 0; gi < 2; ++gi) {
        const int g0 = g0s[gi], G = gns[gi];
        const size_t eoff = (size_t)g0 * NE;
        // --- batched CSR builds (adj graph, then edge graph) ---
        k_izero<<<(G * N_NODES + 255) / 256, 256, 0, stream>>>(cnt, G * N_NODES);
        k_hist<<<dim3(EG, G), 256, 0, stream>>>(adj_dst + eoff, cnt, NE);
        k_scan<<<G, 256, 0, stream>>>(cnt, rowptrA, cursor);
        k_place_sv<<<dim3(EG, G), 256, 0, stream>>>(adj_src + eoff, adj_dst + eoff,
                                                    adj_val + eoff, cursor, psrcA, pvalA, NE);
        k_izero<<<(G * N_NODES + 255) / 256, 256, 0, stream>>>(cnt, G * N_NODES);
        k_hist<<<dim3(EG, G), 256, 0, stream>>>(edge_dst + eoff, cnt, NE);
        k_scan<<<G, 256, 0, stream>>>(cnt, rowptrE, cursor);
        k_place_s<<<dim3(EG, G), 256, 0, stream>>>(edge_src + eoff, edge_dst + eoff,
                                                   cursor, psrcE, NE);
        // --- batched pipeline ---
        // mx = x_hyp @ W_hyp[g].T -> buf1 (bf16)
        gemm_b(5, xhyp_b, Whyp_b + (size_t)g0 * DH * D_INN, nullptr, buf1, nullptr,
               N_NODES, DH, D_INN, G, 0, (size_t)DH * D_INN, NDB, 0, stream);
        k_rowfuse1<<<dim3(N_NODES, G), 256, 0, stream>>>(buf1, xhn, hb + g0 * DH, hb2 + g0);
        k_gather_fuse2<<<dim3(N_NODES, G), 256, 0, stream>>>(rowptrA, psrcA, pvalA, buf1, buf2);
        // d = u @ Wd.T + bd -> buf1
        gemm_b(5, buf2, Wd_b + (size_t)g0 * DH * DH, bd + g0 * DH, buf1, nullptr,
               N_NODES, DH, DH, G, NDB, (size_t)DH * DH, NDB, DH, stream);
        k_gather_add<<<dim3(N_NODES, G), 256, 0, stream>>>(rowptrE, psrcE, buf1, buf2);
        // z = agg @ Wg1.T + bg1 -> buf1
        gemm_b(5, buf2, Wg1_b + (size_t)g0 * DH * DH, bg1 + g0 * DH, buf1, nullptr,
               N_NODES, DH, DH, G, NDB, (size_t)DH * DH, NDB, DH, stream);
        k_zero<<<(G * DH + 255) / 256, 256, 0, stream>>>(csum, G * DH);
        k_zero<<<(G * DH + 255) / 256, 256, 0, stream>>>(csq, G * DH);
        k_colstats<<<dim3(200, G), 256, 0, stream>>>(buf1, csum, csq);
        k_normtanh<<<dim3(N_NODES, G), 256, 0, stream>>>(buf1, csum, csq,
                                                         gamma + g0 * DH, beta + g0 * DH);
        // z_ch = zt @ Wg2.T + bg2 -> buf2
        gemm_b(5, buf1, Wg2_b + (size_t)g0 * DH * DH, bg2 + g0 * DH, buf2, nullptr,
               N_NODES, DH, DH, G, NDB, (size_t)DH * DH, NDB, DH, stream);
        k_gather_ch<<<dim3(NB, G), 256, 0, stream>>>(edge_index, edge_id, buf2, S_b, P_b,
                                                     D_INN + g0 * DH);
    }

    // stage C (bf16 MFMA; gi->S_b, g->P_b, h1->G_b, h2->h2f)
    gemm_b(2, S_b, Wgate_b, bgate, G_b, nullptr, NB, H3, H3, 1, 0, 0, 0, 0, stream);
    gemm_b(4, P_b, Wint_b, bint, S_b, G_b, NB, H3, H3, 1, 0, 0, 0, 0, stream);
    gemm_b(5, S_b, Wout_b, bout, P_b, nullptr, NB, H3, H3, 1, 0, 0, 0, 0, stream);
    gemm_b(3, P_b, Wf1_b, bf1, G_b, nullptr, NB, 1152, H3, 1, 0, 0, 0, 0, stream);
    gemm_b(6, G_b, Wf2_b, bf2, h2f, nullptr, NB, 576, 1152, 1, 0, 0, 0, 0, stream);
    k_final<<<NB, 64, 0, stream>>>(h2f, Wf3, bf3, outp);
}

// Round 7
// 2287.239 us; speedup vs baseline: 1.3955x; 1.3955x over previous
//
#include <hip/hip_runtime.h>
#include <math.h>

#define N_NODES 20000
#define D_INN   512
#define DH      256
#define NCH     7
#define NE      320000
#define NE2     100000
#define NB      8192
#define H3      2304   // 512 + 7*256
#define MAXN    0.996f
#define LOG2E   1.44269504f

typedef unsigned short u16;
typedef __attribute__((ext_vector_type(8))) short bf16x8;
typedef __attribute__((ext_vector_type(4))) float f32x4;

__device__ __forceinline__ u16 f2b(float f) {    // RNE f32 -> bf16 bits
    unsigned int x = __float_as_uint(f);
    unsigned int r = (x + 0x7fffu + ((x >> 16) & 1u)) >> 16;
    return (u16)r;
}
__device__ __forceinline__ float b2f(u16 u) {
    return __uint_as_float(((unsigned int)u) << 16);
}
__device__ __forceinline__ float blo(unsigned int u) { return __uint_as_float(u << 16); }
__device__ __forceinline__ float bhi(unsigned int u) { return __uint_as_float(u & 0xffff0000u); }
__device__ __forceinline__ unsigned int pk2(float a, float b) {
    return (unsigned int)f2b(a) | ((unsigned int)f2b(b) << 16);
}

// ---- fast HW transcendentals (rel err ~1e-5, fine for bf16 tolerance) ----
__device__ __forceinline__ float rcp_f(float x) { return __builtin_amdgcn_rcpf(x); }
__device__ __forceinline__ float exp2_f(float x) { return __builtin_amdgcn_exp2f(x); }
__device__ __forceinline__ float log2_f(float x) { return __builtin_amdgcn_logf(x); }
__device__ __forceinline__ float tanh_fast(float x) {
    float xc = fminf(fmaxf(x, -15.f), 15.f);
    float t = exp2_f(xc * (2.f * LOG2E));
    return (t - 1.f) * rcp_f(t + 1.f);
}
__device__ __forceinline__ float artanh_fast(float x) {
    x = fminf(fmaxf(x, -1.0f + 1e-7f), 1.0f - 1e-7f);
    return 0.34657359f * log2_f((1.f + x) * rcp_f(1.f - x));
}
__device__ __forceinline__ float sigmoid_fast(float x) {
    return rcp_f(1.f + exp2_f(-x * LOG2E));
}

__device__ __forceinline__ float wave_sum(float v) {
    #pragma unroll
    for (int off = 32; off > 0; off >>= 1) v += __shfl_xor(v, off, 64);
    return v;   // all lanes hold the sum
}

__device__ __forceinline__ float block_sum256(float v) {
    __shared__ float sred[4];
    #pragma unroll
    for (int off = 32; off > 0; off >>= 1) v += __shfl_down(v, off, 64);
    int lane = threadIdx.x & 63;
    int w = threadIdx.x >> 6;
    if (lane == 0) sred[w] = v;
    __syncthreads();
    float tot = sred[0] + sred[1] + sred[2] + sred[3];
    __syncthreads();
    return tot;
}

__global__ void k_zero(float* __restrict__ p, int n) {
    int i = blockIdx.x * 256 + threadIdx.x;
    if (i < n) p[i] = 0.0f;
}
__global__ void k_izero(int* __restrict__ p, int n) {
    int i = blockIdx.x * 256 + threadIdx.x;
    if (i < n) p[i] = 0;
}

__global__ void k_f2b(const float* __restrict__ s, u16* __restrict__ d, int n4) {
    int i = blockIdx.x * 256 + threadIdx.x;
    int stride = gridDim.x * 256;
    for (; i < n4; i += stride) {
        float4 v = ((const float4*)s)[i];
        uint2 o; o.x = pk2(v.x, v.y); o.y = pk2(v.z, v.w);
        ((uint2*)d)[i] = o;
    }
}

// ===== batched CSR build =====
__global__ void k_hist(const int* __restrict__ dst, int* __restrict__ cnt, int ne) {
    int z = blockIdx.y;
    dst += (size_t)z * ne;
    cnt += (size_t)z * N_NODES;
    int i = blockIdx.x * 256 + threadIdx.x;
    if (i < ne) atomicAdd(&cnt[dst[i]], 1);
}

__global__ void k_scan(const int* __restrict__ cnt, int* __restrict__ rowptr,
                       int* __restrict__ cursor) {
    int z = blockIdx.x;
    cnt += (size_t)z * N_NODES;
    rowptr += (size_t)z * (N_NODES + 1);
    cursor += (size_t)z * N_NODES;
    __shared__ int part[256];
    int t = threadIdx.x;
    const int CH = (N_NODES + 255) / 256;
    int beg = t * CH;
    int end = beg + CH; if (end > N_NODES) end = N_NODES;
    int s = 0;
    for (int i = beg; i < end; ++i) s += cnt[i];
    part[t] = s;
    __syncthreads();
    for (int off = 1; off < 256; off <<= 1) {
        int v = (t >= off) ? part[t - off] : 0;
        __syncthreads();
        part[t] += v;
        __syncthreads();
    }
    int run = (t == 0) ? 0 : part[t - 1];
    for (int i = beg; i < end; ++i) {
        rowptr[i] = run; cursor[i] = run; run += cnt[i];
    }
    if (t == 255) rowptr[N_NODES] = part[255];
}

__global__ void k_place_sv(const int* __restrict__ src, const int* __restrict__ dst,
                           const float* __restrict__ val, int* __restrict__ cursor,
                           int* __restrict__ psrc, float* __restrict__ pval, int ne) {
    int z = blockIdx.y;
    src += (size_t)z * ne; dst += (size_t)z * ne; val += (size_t)z * ne;
    cursor += (size_t)z * N_NODES; psrc += (size_t)z * ne; pval += (size_t)z * ne;
    int i = blockIdx.x * 256 + threadIdx.x;
    if (i < ne) {
        int d = dst[i];
        int pos = atomicAdd(&cursor[d], 1);
        psrc[pos] = src[i];
        pval[pos] = val[i];
    }
}

__global__ void k_place_s(const int* __restrict__ src, const int* __restrict__ dst,
                          int* __restrict__ cursor, int* __restrict__ psrc, int ne) {
    int z = blockIdx.y;
    src += (size_t)z * ne; dst += (size_t)z * ne;
    cursor += (size_t)z * N_NODES; psrc += (size_t)z * ne;
    int i = blockIdx.x * 256 + threadIdx.x;
    if (i < ne) {
        int d = dst[i];
        int pos = atomicAdd(&cursor[d], 1);
        psrc[pos] = src[i];
    }
}

// x_hyp = proj(expmap0(f1)) -> bf16; clamped row norm -> xhn (f32)
__global__ void k_expmap_proj_in(const float* __restrict__ f1,
                                 u16* __restrict__ xhyp, float* __restrict__ xhn) {
    int r = blockIdx.x, t = threadIdx.x;
    const float* u = f1 + (size_t)r * D_INN;
    float v0 = u[t], v1 = u[t + 256];
    float ss = block_sum256(v0 * v0 + v1 * v1);
    float nraw = sqrtf(ss);
    float n = fmaxf(nraw, 1e-15f);
    float c = tanh_fast(n) * rcp_f(n);
    float ny = c * nraw;
    float np = fmaxf(ny, 1e-15f);
    float s = (np > MAXN) ? MAXN * rcp_f(np) : 1.0f;
    float cs = c * s;
    u16* o = xhyp + (size_t)r * D_INN;
    o[t] = f2b(cs * v0);
    o[t + 256] = f2b(cs * v1);
    if (t == 0) xhn[r] = fminf(np, MAXN);
}

__global__ void k_hb(const float* __restrict__ b_hyp,
                     float* __restrict__ hb, float* __restrict__ hb2) {
    int i = blockIdx.x, t = threadIdx.x;
    float v = b_hyp[i * DH + t];
    float ss = block_sum256(v * v);
    float nraw = sqrtf(ss);
    float n = fmaxf(nraw, 1e-15f);
    float c = tanh_fast(n) * rcp_f(n);
    float ny = c * nraw;
    float np = fmaxf(ny, 1e-15f);
    float s = (np > MAXN) ? MAXN * rcp_f(np) : 1.0f;
    float hv = c * s * v;
    hb[i * DH + t] = hv;
    float s2 = block_sum256(hv * hv);
    if (t == 0) hb2[i] = s2;
}

// wave-per-node (4 nodes/block), lane = 4 feats via uint2; in-place bf16.
// mobius_matvec finalize -> proj -> mobius_add(hb) -> proj -> logmap0
__global__ void k_rowfuse1(u16* __restrict__ T, const float* __restrict__ xhn,
                           const float* __restrict__ hb, const float* __restrict__ hb2) {
    int z = blockIdx.y;
    int n = blockIdx.x * 4 + (threadIdx.x >> 6);
    int lane = threadIdx.x & 63;
    u16* row = T + ((size_t)z * N_NODES + n) * DH;
    const float* hbz = hb + (size_t)z * DH;
    uint2 u = *(const uint2*)(row + lane * 4);
    float m0 = blo(u.x), m1 = bhi(u.x), m2 = blo(u.y), m3 = bhi(u.y);
    float ss = wave_sum(m0 * m0 + m1 * m1 + m2 * m2 + m3 * m3);
    float mxn_raw = sqrtf(ss);
    float mxn = fmaxf(mxn_raw, 1e-15f);
    float xn = xhn[n];
    float tt = tanh_fast(mxn * rcp_f(xn) * artanh_fast(xn));
    float coef = tt * rcp_f(mxn);
    float nres = coef * mxn_raw;
    float np = fmaxf(nres, 1e-15f);
    float s1 = (np > MAXN) ? MAXN * rcp_f(np) : 1.0f;
    float cs = coef * s1;
    float r0 = cs * m0, r1 = cs * m1, r2 = cs * m2, r3 = cs * m3;
    float n1 = fminf(np, MAXN);
    float4 hv = *(const float4*)(hbz + lane * 4);
    float xy = wave_sum(r0 * hv.x + r1 * hv.y + r2 * hv.z + r3 * hv.w);
    float x2 = n1 * n1, y2 = hb2[z];
    float ca = 1.0f + 2.0f * xy + y2;
    float cb = 1.0f - x2;
    float rden = rcp_f(fmaxf(1.0f + 2.0f * xy + x2 * y2, 1e-15f));
    float o0 = (ca * r0 + cb * hv.x) * rden;
    float o1 = (ca * r1 + cb * hv.y) * rden;
    float o2 = (ca * r2 + cb * hv.z) * rden;
    float o3 = (ca * r3 + cb * hv.w) * rden;
    float no2 = wave_sum(o0 * o0 + o1 * o1 + o2 * o2 + o3 * o3);
    float nop = fmaxf(sqrtf(no2), 1e-15f);
    float s2 = (nop > MAXN) ? MAXN * rcp_f(nop) : 1.0f;
    float n2 = fminf(nop, MAXN);
    float fin = artanh_fast(n2) * rcp_f(n2) * s2;
    uint2 o; o.x = pk2(fin * o0, fin * o1); o.y = pk2(fin * o2, fin * o3);
    *(uint2*)(row + lane * 4) = o;
}

// wave-per-node CSR gather + fused rowfuse2 hyperbolic chain -> bf16 out
__global__ void k_gather_fuse2(const int* __restrict__ rowptr, const int* __restrict__ psrc,
                               const float* __restrict__ pval, const u16* __restrict__ xt,
                               u16* __restrict__ out) {
    int z = blockIdx.y;
    rowptr += (size_t)z * (N_NODES + 1);
    psrc += (size_t)z * NE;
    pval += (size_t)z * NE;
    xt += (size_t)z * N_NODES * DH;
    out += (size_t)z * N_NODES * DH;
    int n = blockIdx.x * 4 + (threadIdx.x >> 6);
    int lane = threadIdx.x & 63;
    int beg = rowptr[n], end = rowptr[n + 1];
    float a0 = 0.f, a1 = 0.f, a2 = 0.f, a3 = 0.f;
    for (int i = beg; i < end; ++i) {
        int s = psrc[i];
        float v = pval[i];
        uint2 u = *(const uint2*)(xt + (size_t)s * DH + lane * 4);
        a0 = fmaf(v, blo(u.x), a0);
        a1 = fmaf(v, bhi(u.x), a1);
        a2 = fmaf(v, blo(u.y), a2);
        a3 = fmaf(v, bhi(u.y), a3);
    }
    // expmap0 -> proj -> logmap0 -> relu -> expmap0 -> proj -> logmap0
    float ss = wave_sum(a0 * a0 + a1 * a1 + a2 * a2 + a3 * a3);
    float nraw = sqrtf(ss);
    float n_ = fmaxf(nraw, 1e-15f);
    float c1 = tanh_fast(n_) * rcp_f(n_);
    float nh = c1 * nraw;
    float np1 = fmaxf(nh, 1e-15f);
    float s1 = (np1 > MAXN) ? MAXN * rcp_f(np1) : 1.0f;
    float n1 = fminf(np1, MAXN);
    float cu = artanh_fast(n1) * rcp_f(n1) * s1 * c1;   // support -> u (tangent)
    float u0 = fmaxf(cu * a0, 0.f), u1 = fmaxf(cu * a1, 0.f);
    float u2 = fmaxf(cu * a2, 0.f), u3 = fmaxf(cu * a3, 0.f);
    float ss2 = wave_sum(u0 * u0 + u1 * u1 + u2 * u2 + u3 * u3);
    float n2raw = sqrtf(ss2);
    float n2 = fmaxf(n2raw, 1e-15f);
    float c3 = tanh_fast(n2) * rcp_f(n2);
    float ne = c3 * n2raw;
    float np3 = fmaxf(ne, 1e-15f);
    float s3 = (np3 > MAXN) ? MAXN * rcp_f(np3) : 1.0f;
    float n3 = fminf(np3, MAXN);
    float cf = artanh_fast(n3) * rcp_f(n3) * s3 * c3;
    uint2 o; o.x = pk2(cf * u0, cf * u1); o.y = pk2(cf * u2, cf * u3);
    *(uint2*)(out + (size_t)n * DH + lane * 4) = o;
}

// wave-per-node: agg[n] = d[n] + sum_in d[src]; bf16 in/out, no reductions
__global__ void k_gather_add(const int* __restrict__ rowptr, const int* __restrict__ psrc,
                             const u16* __restrict__ d, u16* __restrict__ out) {
    int z = blockIdx.y;
    rowptr += (size_t)z * (N_NODES + 1);
    psrc += (size_t)z * NE;
    d += (size_t)z * N_NODES * DH;
    out += (size_t)z * N_NODES * DH;
    int n = blockIdx.x * 4 + (threadIdx.x >> 6);
    int lane = threadIdx.x & 63;
    int beg = rowptr[n], end = rowptr[n + 1];
    uint2 u0v = *(const uint2*)(d + (size_t)n * DH + lane * 4);
    float a0 = blo(u0v.x), a1 = bhi(u0v.x), a2 = blo(u0v.y), a3 = bhi(u0v.y);
    for (int i = beg; i < end; ++i) {
        int s = psrc[i];
        uint2 u = *(const uint2*)(d + (size_t)s * DH + lane * 4);
        a0 += blo(u.x); a1 += bhi(u.x); a2 += blo(u.y); a3 += bhi(u.y);
    }
    uint2 o; o.x = pk2(a0, a1); o.y = pk2(a2, a3);
    *(uint2*)(out + (size_t)n * DH + lane * 4) = o;
}

// batched column stats from bf16
__global__ void k_colstats(const u16* __restrict__ zp,
                           float* __restrict__ csum, float* __restrict__ csq) {
    int z = blockIdx.y;
    zp += (size_t)z * N_NODES * DH;
    csum += (size_t)z * DH;
    csq += (size_t)z * DH;
    int t = threadIdx.x;
    int r0 = blockIdx.x * 100;
    float s = 0.0f, q = 0.0f;
    for (int r = r0; r < r0 + 100; ++r) {
        float v = b2f(zp[(size_t)r * DH + t]);
        s += v;
        q += v * v;
    }
    atomicAdd(&csum[t], s);
    atomicAdd(&csq[t], q);
}

// batched batchnorm + tanh, in-place bf16
__global__ void k_normtanh(u16* __restrict__ zp, const float* __restrict__ csum,
                           const float* __restrict__ csq, const float* __restrict__ gamma,
                           const float* __restrict__ beta) {
    int z = blockIdx.y;
    u16* row = zp + ((size_t)z * N_NODES + blockIdx.x) * DH;
    csum += (size_t)z * DH; csq += (size_t)z * DH;
    gamma += (size_t)z * DH; beta += (size_t)z * DH;
    int j = threadIdx.x;
    float mu = csum[j] * (1.0f / N_NODES);
    float var = csq[j] * (1.0f / N_NODES) - mu * mu;
    float inv = __builtin_amdgcn_rsqf(var + 1e-5f);
    float v = (b2f(row[j]) - mu) * inv * gamma[j] + beta[j];
    row[j] = f2b(tanh_fast(v));
}

// f1 slice of S,P (cols 0..511)
__global__ void k_pair0(const int* __restrict__ ei, const int* __restrict__ eid,
                        const float* __restrict__ f1, u16* __restrict__ S,
                        u16* __restrict__ P) {
    int b = blockIdx.x, t = threadIdx.x;
    int e = eid[b];
    int n0 = ei[e], n1 = ei[NE2 + e];
    const float* xa = f1 + (size_t)n0 * D_INN;
    const float* xb = f1 + (size_t)n1 * D_INN;
    u16* so = S + (size_t)b * H3;
    u16* po = P + (size_t)b * H3;
    for (int j = t; j < D_INN; j += 256) {
        float a = xa[j], c = xb[j];
        so[j] = f2b(a + c);
        po[j] = f2b(a * c);
    }
}

// batched channel slice of S,P gathered from z_ch (bf16)
__global__ void k_gather_ch(const int* __restrict__ ei, const int* __restrict__ eid,
                            const u16* __restrict__ zch, u16* __restrict__ S,
                            u16* __restrict__ P, int col0base) {
    int z = blockIdx.y;
    const u16* zp = zch + (size_t)z * N_NODES * DH;
    int col0 = col0base + z * DH;
    int b = blockIdx.x, j = threadIdx.x;
    int e = eid[b];
    int n0 = ei[e], n1 = ei[NE2 + e];
    float a = b2f(zp[(size_t)n0 * DH + j]);
    float c = b2f(zp[(size_t)n1 * DH + j]);
    S[(size_t)b * H3 + col0 + j] = f2b(a + c);
    P[(size_t)b * H3 + col0 + j] = f2b(a * c);
}

__global__ void k_final(const float* __restrict__ h2, const float* __restrict__ Wf3,
                        const float* __restrict__ bf3, float* __restrict__ out) {
    int r = blockIdx.x, t = threadIdx.x;
    const float* hr = h2 + (size_t)r * 576;
    float acc[7] = {0, 0, 0, 0, 0, 0, 0};
    for (int cb = t; cb < 576; cb += 64) {
        float h = hr[cb];
        #pragma unroll
        for (int o = 0; o < 7; ++o) acc[o] = fmaf(h, Wf3[o * 576 + cb], acc[o]);
    }
    #pragma unroll
    for (int o = 0; o < 7; ++o) {
        #pragma unroll
        for (int off = 32; off > 0; off >>= 1) acc[o] += __shfl_down(acc[o], off, 64);
    }
    if (t == 0) {
        #pragma unroll
        for (int o = 0; o < 7; ++o) out[(size_t)r * 7 + o] = acc[o] + bf3[o];
    }
}

// ===== bf16 MFMA GEMM (batched over blockIdx.z with strides). R5 staging:
// reg-staged with LDS 16B-slot swizzle s = kc*16 + ((r + 2*kc)&15) on write
// AND frag read (4-way -> 2-way bank aliasing = free).
// EP: 2=sigmoid->bf16, 3=relu->bf16, 4=aux*relu->bf16, 5=bf16, 6=relu->f32
template <int EP>
__global__ __launch_bounds__(256, 2) void k_gemm_mfma(
    const u16* __restrict__ A, const u16* __restrict__ W,
    const float* __restrict__ bias, void* __restrict__ outv,
    const u16* __restrict__ aux, int M, int N, int K,
    size_t sA, size_t sW, size_t sC, int sBias) {
    __shared__ short As[4096];   // 128x32 bf16
    __shared__ short Ws[4096];
    const int z = blockIdx.z;
    A += (size_t)z * sA;
    W += (size_t)z * sW;
    const size_t zC = (size_t)z * sC;
    const int t = threadIdx.x;
    const int lane = t & 63;
    const int w = t >> 6;
    const int wr = w >> 1, wc = w & 1;
    const int row0 = blockIdx.y * 128, col0 = blockIdx.x * 128;
    const int rkc = lane >> 4, rr = lane & 15;
    const int rdoff = (rkc * 16 + ((rr + 2 * rkc) & 15)) * 8;  // shorts
    f32x4 acc[4][4] = {};
    for (int k0 = 0; k0 < K; k0 += 32) {
        #pragma unroll
        for (int p = 0; p < 2; ++p) {
            int i = t + p * 256;               // 0..511
            int row = i >> 2, kc = i & 3;
            int gr = row0 + row; gr = (gr < M) ? gr : (M - 1);
            int gc = col0 + row; gc = (gc < N) ? gc : (N - 1);
            uint4 va = *(const uint4*)(A + (size_t)gr * K + k0 + kc * 8);
            uint4 vw = *(const uint4*)(W + (size_t)gc * K + k0 + kc * 8);
            int off = (row >> 4) * 512 + (kc * 16 + (((row & 15) + 2 * kc) & 15)) * 8;
            *(uint4*)(As + off) = va;
            *(uint4*)(Ws + off) = vw;
        }
        __syncthreads();
        bf16x8 af[4], bfr[4];
        #pragma unroll
        for (int m = 0; m < 4; ++m)
            af[m] = *(const bf16x8*)(As + (wr * 4 + m) * 512 + rdoff);
        #pragma unroll
        for (int n = 0; n < 4; ++n)
            bfr[n] = *(const bf16x8*)(Ws + (wc * 4 + n) * 512 + rdoff);
        #pragma unroll
        for (int m = 0; m < 4; ++m)
            #pragma unroll
            for (int n = 0; n < 4; ++n)
                acc[m][n] = __builtin_amdgcn_mfma_f32_16x16x32_bf16(af[m], bfr[n], acc[m][n], 0, 0, 0);
        __syncthreads();
    }
    const int cl = lane & 15, rh = (lane >> 4) * 4;
    #pragma unroll
    for (int m = 0; m < 4; ++m) {
        #pragma unroll
        for (int n = 0; n < 4; ++n) {
            int col = col0 + wc * 64 + n * 16 + cl;
            if (col >= N) continue;
            float bv = bias ? bias[z * sBias + col] : 0.0f;
            #pragma unroll
            for (int r = 0; r < 4; ++r) {
                int row = row0 + wr * 64 + m * 16 + rh + r;
                if (row >= M) continue;
                float v = acc[m][n][r] + bv;
                size_t idx = zC + (size_t)row * N + col;
                if (EP == 2) ((u16*)outv)[idx] = f2b(sigmoid_fast(v));
                if (EP == 3) ((u16*)outv)[idx] = f2b(fmaxf(v, 0.0f));
                if (EP == 4) { float g = b2f(aux[idx]); ((u16*)outv)[idx] = f2b(g * fmaxf(v, 0.0f)); }
                if (EP == 5) ((u16*)outv)[idx] = f2b(v);
                if (EP == 6) ((float*)outv)[idx] = fmaxf(v, 0.0f);
            }
        }
    }
}

static inline void gemm_b(int ep, const u16* A, const u16* W, const float* bias, void* out,
                          const u16* aux, int M, int N, int K, int Z,
                          size_t sA, size_t sW, size_t sC, int sBias, hipStream_t st) {
    dim3 g((N + 127) / 128, (M + 127) / 128, Z);
    switch (ep) {
        case 2: k_gemm_mfma<2><<<g, 256, 0, st>>>(A, W, bias, out, aux, M, N, K, sA, sW, sC, sBias); break;
        case 3: k_gemm_mfma<3><<<g, 256, 0, st>>>(A, W, bias, out, aux, M, N, K, sA, sW, sC, sBias); break;
        case 4: k_gemm_mfma<4><<<g, 256, 0, st>>>(A, W, bias, out, aux, M, N, K, sA, sW, sC, sBias); break;
        case 5: k_gemm_mfma<5><<<g, 256, 0, st>>>(A, W, bias, out, aux, M, N, K, sA, sW, sC, sBias); break;
        case 6: k_gemm_mfma<6><<<g, 256, 0, st>>>(A, W, bias, out, aux, M, N, K, sA, sW, sC, sBias); break;
    }
}

static inline void conv_w(const float* s, u16* d, size_t n, hipStream_t st) {
    int n4 = (int)(n / 4);
    int grid = (n4 + 255) / 256;
    if (grid > 2048) grid = 2048;
    k_f2b<<<grid, 256, 0, st>>>(s, d, n4);
}

extern "C" void kernel_launch(void* const* d_in, const int* in_sizes, int n_in, void* d_out,
                              int out_size, void* d_ws, size_t ws_size, hipStream_t stream) {
    const float* f1 = (const float*)d_in[0];
    const int* adj_src = (const int*)d_in[1];
    const int* adj_dst = (const int*)d_in[2];
    const float* adj_val = (const float*)d_in[3];
    const int* edge_src = (const int*)d_in[4];
    const int* edge_dst = (const int*)d_in[5];
    const int* edge_index = (const int*)d_in[6];
    const int* edge_id = (const int*)d_in[7];
    const float* W_hyp = (const float*)d_in[8];
    const float* b_hyp = (const float*)d_in[9];
    const float* Wd = (const float*)d_in[10];
    const float* bd = (const float*)d_in[11];
    const float* Wg1 = (const float*)d_in[12];
    const float* bg1 = (const float*)d_in[13];
    const float* gamma = (const float*)d_in[14];
    const float* beta = (const float*)d_in[15];
    const float* Wg2 = (const float*)d_in[16];
    const float* bg2 = (const float*)d_in[17];
    const float* Wgate = (const float*)d_in[18];
    const float* bgate = (const float*)d_in[19];
    const float* Wint = (const float*)d_in[20];
    const float* bint = (const float*)d_in[21];
    const float* Wout = (const float*)d_in[22];
    const float* bout = (const float*)d_in[23];
    const float* Wf1 = (const float*)d_in[24];
    const float* bf1 = (const float*)d_in[25];
    const float* Wf2 = (const float*)d_in[26];
    const float* bf2 = (const float*)d_in[27];
    const float* Wf3 = (const float*)d_in[28];
    const float* bf3 = (const float*)d_in[29];
    float* outp = (float*)d_out;

    // ---- workspace bump allocator (~245 MB) ----
    char* base = (char*)d_ws;
    size_t off = 0;
    auto alloc = [&](size_t bytes) -> char* {
        char* p = base + off;
        off += (bytes + 255) & ~(size_t)255;
        return p;
    };
    u16* Whyp_b = (u16*)alloc((size_t)NCH * DH * D_INN * 2);
    u16* Wd_b   = (u16*)alloc((size_t)NCH * DH * DH * 2);
    u16* Wg1_b  = (u16*)alloc((size_t)NCH * DH * DH * 2);
    u16* Wg2_b  = (u16*)alloc((size_t)NCH * DH * DH * 2);
    u16* Wgate_b = (u16*)alloc((size_t)H3 * H3 * 2);
    u16* Wint_b  = (u16*)alloc((size_t)H3 * H3 * 2);
    u16* Wout_b  = (u16*)alloc((size_t)H3 * H3 * 2);
    u16* Wf1_b   = (u16*)alloc((size_t)1152 * H3 * 2);
    u16* Wf2_b   = (u16*)alloc((size_t)576 * 1152 * 2);
    u16* S_b = (u16*)alloc((size_t)NB * H3 * 2);
    u16* P_b = (u16*)alloc((size_t)NB * H3 * 2);
    const size_t NDB = (size_t)N_NODES * DH;       // per-channel elems
    u16* buf1 = (u16*)alloc(4 * NDB * 2);          // group ping
    u16* buf2 = (u16*)alloc(4 * NDB * 2);          // group pong
    u16* xhyp_b = (u16*)alloc((size_t)N_NODES * D_INN * 2);
    // batched CSR scratch (max group = 4 channels)
    int* cnt = (int*)alloc(4 * (size_t)N_NODES * 4);
    int* cursor = (int*)alloc(4 * (size_t)N_NODES * 4);
    int* rowptrA = (int*)alloc(4 * (size_t)(N_NODES + 1) * 4);
    int* rowptrE = (int*)alloc(4 * (size_t)(N_NODES + 1) * 4);
    int* psrcA = (int*)alloc(4 * (size_t)NE * 4);
    float* pvalA = (float*)alloc(4 * (size_t)NE * 4);
    int* psrcE = (int*)alloc(4 * (size_t)NE * 4);
    float* xhn = (float*)alloc((size_t)N_NODES * 4);
    float* hb = (float*)alloc((size_t)NCH * DH * 4);
    float* hb2 = (float*)alloc(NCH * 4);
    float* csum = (float*)alloc((size_t)4 * DH * 4);
    float* csq = (float*)alloc((size_t)4 * DH * 4);
    // stage-C overlays (GNN buffers dead by then)
    u16* G_b = buf1;                 // 37.75 MB <= 40.96
    float* h2f = (float*)buf2;       // 18.87 MB <= 40.96

    const int EG = (NE + 255) / 256;

    conv_w(W_hyp, Whyp_b, (size_t)NCH * DH * D_INN, stream);
    conv_w(Wd, Wd_b, (size_t)NCH * DH * DH, stream);
    conv_w(Wg1, Wg1_b, (size_t)NCH * DH * DH, stream);
    conv_w(Wg2, Wg2_b, (size_t)NCH * DH * DH, stream);
    conv_w(Wgate, Wgate_b, (size_t)H3 * H3, stream);
    conv_w(Wint, Wint_b, (size_t)H3 * H3, stream);
    conv_w(Wout, Wout_b, (size_t)H3 * H3, stream);
    conv_w(Wf1, Wf1_b, (size_t)1152 * H3, stream);
    conv_w(Wf2, Wf2_b, (size_t)576 * 1152, stream);

    k_expmap_proj_in<<<N_NODES, 256, 0, stream>>>(f1, xhyp_b, xhn);
    k_hb<<<NCH, 256, 0, stream>>>(b_hyp, hb, hb2);
    k_pair0<<<NB, 256, 0, stream>>>(edge_index, edge_id, f1, S_b, P_b);

    const int g0s[2] = {0, 4};
    const int gns[2] = {4, 3};
    for (int gi = 0; gi < 2; ++gi) {
        const int g0 = g0s[gi], G = gns[gi];
        const size_t eoff = (size_t)g0 * NE;
        // --- batched CSR builds (adj graph, then edge graph) ---
        k_izero<<<(G * N_NODES + 255) / 256, 256, 0, stream>>>(cnt, G * N_NODES);
        k_hist<<<dim3(EG, G), 256, 0, stream>>>(adj_dst + eoff, cnt, NE);
        k_scan<<<G, 256, 0, stream>>>(cnt, rowptrA, cursor);
        k_place_sv<<<dim3(EG, G), 256, 0, stream>>>(adj_src + eoff, adj_dst + eoff,
                                                    adj_val + eoff, cursor, psrcA, pvalA, NE);
        k_izero<<<(G * N_NODES + 255) / 256, 256, 0, stream>>>(cnt, G * N_NODES);
        k_hist<<<dim3(EG, G), 256, 0, stream>>>(edge_dst + eoff, cnt, NE);
        k_scan<<<G, 256, 0, stream>>>(cnt, rowptrE, cursor);
        k_place_s<<<dim3(EG, G), 256, 0, stream>>>(edge_src + eoff, edge_dst + eoff,
                                                   cursor, psrcE, NE);
        // --- batched pipeline ---
        // mx = x_hyp @ W_hyp[g].T -> buf1 (bf16)
        gemm_b(5, xhyp_b, Whyp_b + (size_t)g0 * DH * D_INN, nullptr, buf1, nullptr,
               N_NODES, DH, D_INN, G, 0, (size_t)DH * D_INN, NDB, 0, stream);
        k_rowfuse1<<<dim3(N_NODES / 4, G), 256, 0, stream>>>(buf1, xhn, hb + g0 * DH, hb2 + g0);
        k_gather_fuse2<<<dim3(N_NODES / 4, G), 256, 0, stream>>>(rowptrA, psrcA, pvalA, buf1, buf2);
        // d = u @ Wd.T + bd -> buf1
        gemm_b(5, buf2, Wd_b + (size_t)g0 * DH * DH, bd + g0 * DH, buf1, nullptr,
               N_NODES, DH, DH, G, NDB, (size_t)DH * DH, NDB, DH, stream);
        k_gather_add<<<dim3(N_NODES / 4, G), 256, 0, stream>>>(rowptrE, psrcE, buf1, buf2);
        // z = agg @ Wg1.T + bg1 -> buf1
        gemm_b(5, buf2, Wg1_b + (size_t)g0 * DH * DH, bg1 + g0 * DH, buf1, nullptr,
               N_NODES, DH, DH, G, NDB, (size_t)DH * DH, NDB, DH, stream);
        k_zero<<<(G * DH + 255) / 256, 256, 0, stream>>>(csum, G * DH);
        k_zero<<<(G * DH + 255) / 256, 256, 0, stream>>>(csq, G * DH);
        k_colstats<<<dim3(200, G), 256, 0, stream>>>(buf1, csum, csq);
        k_normtanh<<<dim3(N_NODES, G), 256, 0, stream>>>(buf1, csum, csq,
                                                         gamma + g0 * DH, beta + g0 * DH);
        // z_ch = zt @ Wg2.T + bg2 -> buf2
        gemm_b(5, buf1, Wg2_b + (size_t)g0 * DH * DH, bg2 + g0 * DH, buf2, nullptr,
               N_NODES, DH, DH, G, NDB, (size_t)DH * DH, NDB, DH, stream);
        k_gather_ch<<<dim3(NB, G), 256, 0, stream>>>(edge_index, edge_id, buf2, S_b, P_b,
                                                     D_INN + g0 * DH);
    }

    // stage C (bf16 MFMA; gi->S_b, g->P_b, h1->G_b, h2->h2f)
    gemm_b(2, S_b, Wgate_b, bgate, G_b, nullptr, NB, H3, H3, 1, 0, 0, 0, 0, stream);
    gemm_b(4, P_b, Wint_b, bint, S_b, G_b, NB, H3, H3, 1, 0, 0, 0, 0, stream);
    gemm_b(5, S_b, Wout_b, bout, P_b, nullptr, NB, H3, H3, 1, 0, 0, 0, 0, stream);
    gemm_b(3, P_b, Wf1_b, bf1, G_b, nullptr, NB, 1152, H3, 1, 0, 0, 0, 0, stream);
    gemm_b(6, G_b, Wf2_b, bf2, h2f, nullptr, NB, 576, 1152, 1, 0, 0, 0, 0, stream);
    k_final<<<NB, 64, 0, stream>>>(h2f, Wf3, bf3, outp);
}

// Round 8
// 2148.114 us; speedup vs baseline: 1.4859x; 1.0648x over previous
//
#include <hip/hip_runtime.h>
#include <math.h>

#define N_NODES 20000
#define D_INN   512
#define DH      256
#define NCH     7
#define NE      320000
#define NE2     100000
#define NB      8192
#define H3      2304   // 512 + 7*256
#define MAXN    0.996f
#define LOG2E   1.44269504f

typedef unsigned short u16;
typedef __attribute__((ext_vector_type(8))) short bf16x8;
typedef __attribute__((ext_vector_type(4))) float f32x4;

__device__ __forceinline__ u16 f2b(float f) {    // RNE f32 -> bf16 bits
    unsigned int x = __float_as_uint(f);
    unsigned int r = (x + 0x7fffu + ((x >> 16) & 1u)) >> 16;
    return (u16)r;
}
__device__ __forceinline__ float b2f(u16 u) {
    return __uint_as_float(((unsigned int)u) << 16);
}
__device__ __forceinline__ float blo(unsigned int u) { return __uint_as_float(u << 16); }
__device__ __forceinline__ float bhi(unsigned int u) { return __uint_as_float(u & 0xffff0000u); }
__device__ __forceinline__ unsigned int pk2(float a, float b) {
    return (unsigned int)f2b(a) | ((unsigned int)f2b(b) << 16);
}

// ---- fast HW transcendentals (rel err ~1e-5, fine for bf16 tolerance) ----
__device__ __forceinline__ float rcp_f(float x) { return __builtin_amdgcn_rcpf(x); }
__device__ __forceinline__ float exp2_f(float x) { return __builtin_amdgcn_exp2f(x); }
__device__ __forceinline__ float log2_f(float x) { return __builtin_amdgcn_logf(x); }
__device__ __forceinline__ float tanh_fast(float x) {
    float xc = fminf(fmaxf(x, -15.f), 15.f);
    float t = exp2_f(xc * (2.f * LOG2E));
    return (t - 1.f) * rcp_f(t + 1.f);
}
__device__ __forceinline__ float artanh_fast(float x) {
    x = fminf(fmaxf(x, -1.0f + 1e-7f), 1.0f - 1e-7f);
    return 0.34657359f * log2_f((1.f + x) * rcp_f(1.f - x));
}
__device__ __forceinline__ float sigmoid_fast(float x) {
    return rcp_f(1.f + exp2_f(-x * LOG2E));
}

__device__ __forceinline__ float wave_sum(float v) {
    #pragma unroll
    for (int off = 32; off > 0; off >>= 1) v += __shfl_xor(v, off, 64);
    return v;
}

__device__ __forceinline__ float block_sum256(float v) {
    __shared__ float sred[4];
    #pragma unroll
    for (int off = 32; off > 0; off >>= 1) v += __shfl_down(v, off, 64);
    int lane = threadIdx.x & 63;
    int w = threadIdx.x >> 6;
    if (lane == 0) sred[w] = v;
    __syncthreads();
    float tot = sred[0] + sred[1] + sred[2] + sred[3];
    __syncthreads();
    return tot;
}

__global__ void k_zero(float* __restrict__ p, int n) {
    int i = blockIdx.x * 256 + threadIdx.x;
    if (i < n) p[i] = 0.0f;
}
__global__ void k_izero(int* __restrict__ p, int n) {
    int i = blockIdx.x * 256 + threadIdx.x;
    if (i < n) p[i] = 0;
}

__global__ void k_f2b(const float* __restrict__ s, u16* __restrict__ d, int n4) {
    int i = blockIdx.x * 256 + threadIdx.x;
    int stride = gridDim.x * 256;
    for (; i < n4; i += stride) {
        float4 v = ((const float4*)s)[i];
        uint2 o; o.x = pk2(v.x, v.y); o.y = pk2(v.z, v.w);
        ((uint2*)d)[i] = o;
    }
}

// ===== merged CSR build: 2G z-slices (z<G: adj graph, z>=G: edge graph) =====
__global__ void k_hist2(const int* __restrict__ adjd, const int* __restrict__ edged,
                        int* __restrict__ cnt, int G) {
    int z = blockIdx.y;
    const int* dst = (z < G) ? adjd + (size_t)z * NE : edged + (size_t)(z - G) * NE;
    cnt += (size_t)z * N_NODES;
    int i = blockIdx.x * 256 + threadIdx.x;
    if (i < NE) atomicAdd(&cnt[dst[i]], 1);
}

// one block per slice; cnt becomes the cursor array in-place
__global__ void k_scan(int* __restrict__ cnt, int* __restrict__ rowptr) {
    int z = blockIdx.x;
    cnt += (size_t)z * N_NODES;
    rowptr += (size_t)z * (N_NODES + 1);
    __shared__ int part[256];
    int t = threadIdx.x;
    const int CH = (N_NODES + 255) / 256;
    int beg = t * CH;
    int end = beg + CH; if (end > N_NODES) end = N_NODES;
    int s = 0;
    for (int i = beg; i < end; ++i) s += cnt[i];
    part[t] = s;
    __syncthreads();
    for (int off = 1; off < 256; off <<= 1) {
        int v = (t >= off) ? part[t - off] : 0;
        __syncthreads();
        part[t] += v;
        __syncthreads();
    }
    int run = (t == 0) ? 0 : part[t - 1];
    for (int i = beg; i < end; ++i) {
        int c = cnt[i];
        rowptr[i] = run;
        cnt[i] = run;      // cursor init (in-place)
        run += c;
    }
    if (t == 255) rowptr[N_NODES] = part[255];
}

__global__ void k_place2(const int* __restrict__ adjs, const int* __restrict__ adjd,
                         const float* __restrict__ adjv, const int* __restrict__ edges,
                         const int* __restrict__ edged, int* __restrict__ cursor,
                         int* __restrict__ psrc, float* __restrict__ pval, int G) {
    int z = blockIdx.y;
    bool isadj = z < G;
    const int* src = isadj ? adjs + (size_t)z * NE : edges + (size_t)(z - G) * NE;
    const int* dst = isadj ? adjd + (size_t)z * NE : edged + (size_t)(z - G) * NE;
    cursor += (size_t)z * N_NODES;
    psrc += (size_t)z * NE;
    int i = blockIdx.x * 256 + threadIdx.x;
    if (i < NE) {
        int d = dst[i];
        int pos = atomicAdd(&cursor[d], 1);
        psrc[pos] = src[i];
        if (isadj) pval[(size_t)z * NE + pos] = adjv[(size_t)z * NE + i];
    }
}

// x_hyp = proj(expmap0(f1)) -> bf16; clamped row norm -> xhn (f32)
__global__ void k_expmap_proj_in(const float* __restrict__ f1,
                                 u16* __restrict__ xhyp, float* __restrict__ xhn) {
    int r = blockIdx.x, t = threadIdx.x;
    const float* u = f1 + (size_t)r * D_INN;
    float v0 = u[t], v1 = u[t + 256];
    float ss = block_sum256(v0 * v0 + v1 * v1);
    float nraw = sqrtf(ss);
    float n = fmaxf(nraw, 1e-15f);
    float c = tanh_fast(n) * rcp_f(n);
    float ny = c * nraw;
    float np = fmaxf(ny, 1e-15f);
    float s = (np > MAXN) ? MAXN * rcp_f(np) : 1.0f;
    float cs = c * s;
    u16* o = xhyp + (size_t)r * D_INN;
    o[t] = f2b(cs * v0);
    o[t + 256] = f2b(cs * v1);
    if (t == 0) xhn[r] = fminf(np, MAXN);
}

__global__ void k_hb(const float* __restrict__ b_hyp,
                     float* __restrict__ hb, float* __restrict__ hb2) {
    int i = blockIdx.x, t = threadIdx.x;
    float v = b_hyp[i * DH + t];
    float ss = block_sum256(v * v);
    float nraw = sqrtf(ss);
    float n = fmaxf(nraw, 1e-15f);
    float c = tanh_fast(n) * rcp_f(n);
    float ny = c * nraw;
    float np = fmaxf(ny, 1e-15f);
    float s = (np > MAXN) ? MAXN * rcp_f(np) : 1.0f;
    float hv = c * s * v;
    hb[i * DH + t] = hv;
    float s2 = block_sum256(hv * hv);
    if (t == 0) hb2[i] = s2;
}

// wave-per-node (4 nodes/block), lane = 4 feats via uint2; in-place bf16.
__global__ void k_rowfuse1(u16* __restrict__ T, const float* __restrict__ xhn,
                           const float* __restrict__ hb, const float* __restrict__ hb2) {
    int z = blockIdx.y;
    int n = blockIdx.x * 4 + (threadIdx.x >> 6);
    int lane = threadIdx.x & 63;
    u16* row = T + ((size_t)z * N_NODES + n) * DH;
    const float* hbz = hb + (size_t)z * DH;
    uint2 u = *(const uint2*)(row + lane * 4);
    float m0 = blo(u.x), m1 = bhi(u.x), m2 = blo(u.y), m3 = bhi(u.y);
    float ss = wave_sum(m0 * m0 + m1 * m1 + m2 * m2 + m3 * m3);
    float mxn_raw = sqrtf(ss);
    float mxn = fmaxf(mxn_raw, 1e-15f);
    float xn = xhn[n];
    float tt = tanh_fast(mxn * rcp_f(xn) * artanh_fast(xn));
    float coef = tt * rcp_f(mxn);
    float nres = coef * mxn_raw;
    float np = fmaxf(nres, 1e-15f);
    float s1 = (np > MAXN) ? MAXN * rcp_f(np) : 1.0f;
    float cs = coef * s1;
    float r0 = cs * m0, r1 = cs * m1, r2 = cs * m2, r3 = cs * m3;
    float n1 = fminf(np, MAXN);
    float4 hv = *(const float4*)(hbz + lane * 4);
    float xy = wave_sum(r0 * hv.x + r1 * hv.y + r2 * hv.z + r3 * hv.w);
    float x2 = n1 * n1, y2 = hb2[z];
    float ca = 1.0f + 2.0f * xy + y2;
    float cb = 1.0f - x2;
    float rden = rcp_f(fmaxf(1.0f + 2.0f * xy + x2 * y2, 1e-15f));
    float o0 = (ca * r0 + cb * hv.x) * rden;
    float o1 = (ca * r1 + cb * hv.y) * rden;
    float o2 = (ca * r2 + cb * hv.z) * rden;
    float o3 = (ca * r3 + cb * hv.w) * rden;
    float no2 = wave_sum(o0 * o0 + o1 * o1 + o2 * o2 + o3 * o3);
    float nop = fmaxf(sqrtf(no2), 1e-15f);
    float s2 = (nop > MAXN) ? MAXN * rcp_f(nop) : 1.0f;
    float n2 = fminf(nop, MAXN);
    float fin = artanh_fast(n2) * rcp_f(n2) * s2;
    uint2 o; o.x = pk2(fin * o0, fin * o1); o.y = pk2(fin * o2, fin * o3);
    *(uint2*)(row + lane * 4) = o;
}

// wave-per-node CSR gather + fused rowfuse2 hyperbolic chain -> bf16 out
__global__ void k_gather_fuse2(const int* __restrict__ rowptr, const int* __restrict__ psrc,
                               const float* __restrict__ pval, const u16* __restrict__ xt,
                               u16* __restrict__ out) {
    int z = blockIdx.y;
    rowptr += (size_t)z * (N_NODES + 1);
    psrc += (size_t)z * NE;
    pval += (size_t)z * NE;
    xt += (size_t)z * N_NODES * DH;
    out += (size_t)z * N_NODES * DH;
    int n = blockIdx.x * 4 + (threadIdx.x >> 6);
    int lane = threadIdx.x & 63;
    int beg = rowptr[n], end = rowptr[n + 1];
    float a0 = 0.f, a1 = 0.f, a2 = 0.f, a3 = 0.f;
    for (int i = beg; i < end; ++i) {
        int s = psrc[i];
        float v = pval[i];
        uint2 u = *(const uint2*)(xt + (size_t)s * DH + lane * 4);
        a0 = fmaf(v, blo(u.x), a0);
        a1 = fmaf(v, bhi(u.x), a1);
        a2 = fmaf(v, blo(u.y), a2);
        a3 = fmaf(v, bhi(u.y), a3);
    }
    float ss = wave_sum(a0 * a0 + a1 * a1 + a2 * a2 + a3 * a3);
    float nraw = sqrtf(ss);
    float n_ = fmaxf(nraw, 1e-15f);
    float c1 = tanh_fast(n_) * rcp_f(n_);
    float nh = c1 * nraw;
    float np1 = fmaxf(nh, 1e-15f);
    float s1 = (np1 > MAXN) ? MAXN * rcp_f(np1) : 1.0f;
    float n1 = fminf(np1, MAXN);
    float cu = artanh_fast(n1) * rcp_f(n1) * s1 * c1;
    float u0 = fmaxf(cu * a0, 0.f), u1 = fmaxf(cu * a1, 0.f);
    float u2 = fmaxf(cu * a2, 0.f), u3 = fmaxf(cu * a3, 0.f);
    float ss2 = wave_sum(u0 * u0 + u1 * u1 + u2 * u2 + u3 * u3);
    float n2raw = sqrtf(ss2);
    float n2 = fmaxf(n2raw, 1e-15f);
    float c3 = tanh_fast(n2) * rcp_f(n2);
    float ne = c3 * n2raw;
    float np3 = fmaxf(ne, 1e-15f);
    float s3 = (np3 > MAXN) ? MAXN * rcp_f(np3) : 1.0f;
    float n3 = fminf(np3, MAXN);
    float cf = artanh_fast(n3) * rcp_f(n3) * s3 * c3;
    uint2 o; o.x = pk2(cf * u0, cf * u1); o.y = pk2(cf * u2, cf * u3);
    *(uint2*)(out + (size_t)n * DH + lane * 4) = o;
}

// wave-per-node: agg[n] = d[n] + sum_in d[src]; bf16 in/out
__global__ void k_gather_add(const int* __restrict__ rowptr, const int* __restrict__ psrc,
                             const u16* __restrict__ d, u16* __restrict__ out) {
    int z = blockIdx.y;
    rowptr += (size_t)z * (N_NODES + 1);
    psrc += (size_t)z * NE;
    d += (size_t)z * N_NODES * DH;
    out += (size_t)z * N_NODES * DH;
    int n = blockIdx.x * 4 + (threadIdx.x >> 6);
    int lane = threadIdx.x & 63;
    int beg = rowptr[n], end = rowptr[n + 1];
    uint2 u0v = *(const uint2*)(d + (size_t)n * DH + lane * 4);
    float a0 = blo(u0v.x), a1 = bhi(u0v.x), a2 = blo(u0v.y), a3 = bhi(u0v.y);
    for (int i = beg; i < end; ++i) {
        int s = psrc[i];
        uint2 u = *(const uint2*)(d + (size_t)s * DH + lane * 4);
        a0 += blo(u.x); a1 += bhi(u.x); a2 += blo(u.y); a3 += bhi(u.y);
    }
    uint2 o; o.x = pk2(a0, a1); o.y = pk2(a2, a3);
    *(uint2*)(out + (size_t)n * DH + lane * 4) = o;
}

// batched column stats from bf16
__global__ void k_colstats(const u16* __restrict__ zp,
                           float* __restrict__ csum, float* __restrict__ csq) {
    int z = blockIdx.y;
    zp += (size_t)z * N_NODES * DH;
    csum += (size_t)z * DH;
    csq += (size_t)z * DH;
    int t = threadIdx.x;
    int r0 = blockIdx.x * 100;
    float s = 0.0f, q = 0.0f;
    for (int r = r0; r < r0 + 100; ++r) {
        float v = b2f(zp[(size_t)r * DH + t]);
        s += v;
        q += v * v;
    }
    atomicAdd(&csum[t], s);
    atomicAdd(&csq[t], q);
}

// grid-stride uint2 batchnorm + tanh, in-place bf16 (total4 = G*N*DH/4)
__global__ void k_normtanh_v(u16* __restrict__ zp, const float* __restrict__ csum,
                             const float* __restrict__ csq, const float* __restrict__ gamma,
                             const float* __restrict__ beta, int total4) {
    const float inv_n = 1.0f / N_NODES;
    int i = blockIdx.x * 256 + threadIdx.x;
    int stride = gridDim.x * 256;
    for (; i < total4; i += stride) {
        int e0 = i * 4;
        int z = e0 / (N_NODES * DH);
        int j0 = e0 & (DH - 1);
        int zb = z * DH + j0;
        uint2 u = ((uint2*)zp)[i];
        float v[4] = {blo(u.x), bhi(u.x), blo(u.y), bhi(u.y)};
        #pragma unroll
        for (int k = 0; k < 4; ++k) {
            float mu = csum[zb + k] * inv_n;
            float var = csq[zb + k] * inv_n - mu * mu;
            float inv = __builtin_amdgcn_rsqf(var + 1e-5f);
            v[k] = tanh_fast((v[k] - mu) * inv * gamma[zb + k] + beta[zb + k]);
        }
        uint2 o; o.x = pk2(v[0], v[1]); o.y = pk2(v[2], v[3]);
        ((uint2*)zp)[i] = o;
    }
}

// f1 slice of S,P (cols 0..511): thread t -> 2 cols via float2, packed u32 store
__global__ void k_pair0(const int* __restrict__ ei, const int* __restrict__ eid,
                        const float* __restrict__ f1, u16* __restrict__ S,
                        u16* __restrict__ P) {
    int b = blockIdx.x, t = threadIdx.x;
    int e = eid[b];
    int n0 = ei[e], n1 = ei[NE2 + e];
    float2 a = *(const float2*)(f1 + (size_t)n0 * D_INN + t * 2);
    float2 c = *(const float2*)(f1 + (size_t)n1 * D_INN + t * 2);
    ((unsigned int*)(S + (size_t)b * H3))[t] = pk2(a.x + c.x, a.y + c.y);
    ((unsigned int*)(P + (size_t)b * H3))[t] = pk2(a.x * c.x, a.y * c.y);
}

// batched channel slice of S,P from z_ch; 4 edges/block, uint2 lanes
__global__ void k_gather_ch(const int* __restrict__ ei, const int* __restrict__ eid,
                            const u16* __restrict__ zch, u16* __restrict__ S,
                            u16* __restrict__ P, int col0base) {
    int z = blockIdx.y;
    const u16* zp = zch + (size_t)z * N_NODES * DH;
    int col0 = col0base + z * DH;
    int b = blockIdx.x * 4 + (threadIdx.x >> 6);
    int lane = threadIdx.x & 63;
    int e = eid[b];
    int n0 = ei[e], n1 = ei[NE2 + e];
    uint2 ua = *(const uint2*)(zp + (size_t)n0 * DH + lane * 4);
    uint2 ub = *(const uint2*)(zp + (size_t)n1 * DH + lane * 4);
    float a0 = blo(ua.x), a1 = bhi(ua.x), a2 = blo(ua.y), a3 = bhi(ua.y);
    float c0 = blo(ub.x), c1 = bhi(ub.x), c2 = blo(ub.y), c3 = bhi(ub.y);
    uint2 so; so.x = pk2(a0 + c0, a1 + c1); so.y = pk2(a2 + c2, a3 + c3);
    uint2 po; po.x = pk2(a0 * c0, a1 * c1); po.y = pk2(a2 * c2, a3 * c3);
    *(uint2*)(S + (size_t)b * H3 + col0 + lane * 4) = so;
    *(uint2*)(P + (size_t)b * H3 + col0 + lane * 4) = po;
}

__global__ void k_final(const float* __restrict__ h2, const float* __restrict__ Wf3,
                        const float* __restrict__ bf3, float* __restrict__ out) {
    int r = blockIdx.x, t = threadIdx.x;
    const float* hr = h2 + (size_t)r * 576;
    float acc[7] = {0, 0, 0, 0, 0, 0, 0};
    for (int cb = t; cb < 576; cb += 64) {
        float h = hr[cb];
        #pragma unroll
        for (int o = 0; o < 7; ++o) acc[o] = fmaf(h, Wf3[o * 576 + cb], acc[o]);
    }
    #pragma unroll
    for (int o = 0; o < 7; ++o) {
        #pragma unroll
        for (int off = 32; off > 0; off >>= 1) acc[o] += __shfl_down(acc[o], off, 64);
    }
    if (t == 0) {
        #pragma unroll
        for (int o = 0; o < 7; ++o) out[(size_t)r * 7 + o] = acc[o] + bf3[o];
    }
}

// ===== bf16 MFMA GEMM (batched over blockIdx.z with strides).
// Reg-staged, LDS 16B-slot swizzle s = kc*16 + ((r+2*kc)&15) on write AND read.
// XCD-aware bijective block swizzle (m204) per z-slice: each XCD gets a
// contiguous chunk of flattened (y-major) tile ids -> A row-panels become
// XCD-L2-local instead of being fetched by all 8 XCDs.
// EP: 2=sigmoid->bf16, 3=relu->bf16, 4=aux*relu->bf16, 5=bf16, 6=relu->f32
template <int EP>
__global__ __launch_bounds__(256, 2) void k_gemm_mfma(
    const u16* __restrict__ A, const u16* __restrict__ W,
    const float* __restrict__ bias, void* __restrict__ outv,
    const u16* __restrict__ aux, int M, int N, int K,
    size_t sA, size_t sW, size_t sC, int sBias) {
    __shared__ short As[4096];   // 128x32 bf16
    __shared__ short Ws[4096];
    const int z = blockIdx.z;
    A += (size_t)z * sA;
    W += (size_t)z * sW;
    const size_t zC = (size_t)z * sC;
    // XCD bijective swizzle within this z-slice
    const int gx = gridDim.x;
    const int nwg = gx * gridDim.y;
    const int orig = blockIdx.y * gx + blockIdx.x;
    const int q = nwg >> 3, r8 = nwg & 7, xcd = orig & 7;
    const int wg = (xcd < r8 ? xcd * (q + 1) : r8 * (q + 1) + (xcd - r8) * q) + (orig >> 3);
    const int row0 = (wg / gx) * 128, col0 = (wg % gx) * 128;
    const int t = threadIdx.x;
    const int lane = t & 63;
    const int w = t >> 6;
    const int wr = w >> 1, wc = w & 1;
    const int rkc = lane >> 4, rr = lane & 15;
    const int rdoff = (rkc * 16 + ((rr + 2 * rkc) & 15)) * 8;  // shorts
    f32x4 acc[4][4] = {};
    for (int k0 = 0; k0 < K; k0 += 32) {
        #pragma unroll
        for (int p = 0; p < 2; ++p) {
            int i = t + p * 256;               // 0..511
            int row = i >> 2, kc = i & 3;
            int gr = row0 + row; gr = (gr < M) ? gr : (M - 1);
            int gc = col0 + row; gc = (gc < N) ? gc : (N - 1);
            uint4 va = *(const uint4*)(A + (size_t)gr * K + k0 + kc * 8);
            uint4 vw = *(const uint4*)(W + (size_t)gc * K + k0 + kc * 8);
            int off = (row >> 4) * 512 + (kc * 16 + (((row & 15) + 2 * kc) & 15)) * 8;
            *(uint4*)(As + off) = va;
            *(uint4*)(Ws + off) = vw;
        }
        __syncthreads();
        bf16x8 af[4], bfr[4];
        #pragma unroll
        for (int m = 0; m < 4; ++m)
            af[m] = *(const bf16x8*)(As + (wr * 4 + m) * 512 + rdoff);
        #pragma unroll
        for (int n = 0; n < 4; ++n)
            bfr[n] = *(const bf16x8*)(Ws + (wc * 4 + n) * 512 + rdoff);
        #pragma unroll
        for (int m = 0; m < 4; ++m)
            #pragma unroll
            for (int n = 0; n < 4; ++n)
                acc[m][n] = __builtin_amdgcn_mfma_f32_16x16x32_bf16(af[m], bfr[n], acc[m][n], 0, 0, 0);
        __syncthreads();
    }
    const int cl = lane & 15, rh = (lane >> 4) * 4;
    #pragma unroll
    for (int m = 0; m < 4; ++m) {
        #pragma unroll
        for (int n = 0; n < 4; ++n) {
            int col = col0 + wc * 64 + n * 16 + cl;
            if (col >= N) continue;
            float bv = bias ? bias[z * sBias + col] : 0.0f;
            #pragma unroll
            for (int r = 0; r < 4; ++r) {
                int row = row0 + wr * 64 + m * 16 + rh + r;
                if (row >= M) continue;
                float v = acc[m][n][r] + bv;
                size_t idx = zC + (size_t)row * N + col;
                if (EP == 2) ((u16*)outv)[idx] = f2b(sigmoid_fast(v));
                if (EP == 3) ((u16*)outv)[idx] = f2b(fmaxf(v, 0.0f));
                if (EP == 4) { float g = b2f(aux[idx]); ((u16*)outv)[idx] = f2b(g * fmaxf(v, 0.0f)); }
                if (EP == 5) ((u16*)outv)[idx] = f2b(v);
                if (EP == 6) ((float*)outv)[idx] = fmaxf(v, 0.0f);
            }
        }
    }
}

static inline void gemm_b(int ep, const u16* A, const u16* W, const float* bias, void* out,
                          const u16* aux, int M, int N, int K, int Z,
                          size_t sA, size_t sW, size_t sC, int sBias, hipStream_t st) {
    dim3 g((N + 127) / 128, (M + 127) / 128, Z);
    switch (ep) {
        case 2: k_gemm_mfma<2><<<g, 256, 0, st>>>(A, W, bias, out, aux, M, N, K, sA, sW, sC, sBias); break;
        case 3: k_gemm_mfma<3><<<g, 256, 0, st>>>(A, W, bias, out, aux, M, N, K, sA, sW, sC, sBias); break;
        case 4: k_gemm_mfma<4><<<g, 256, 0, st>>>(A, W, bias, out, aux, M, N, K, sA, sW, sC, sBias); break;
        case 5: k_gemm_mfma<5><<<g, 256, 0, st>>>(A, W, bias, out, aux, M, N, K, sA, sW, sC, sBias); break;
        case 6: k_gemm_mfma<6><<<g, 256, 0, st>>>(A, W, bias, out, aux, M, N, K, sA, sW, sC, sBias); break;
    }
}

static inline void conv_w(const float* s, u16* d, size_t n, hipStream_t st) {
    int n4 = (int)(n / 4);
    int grid = (n4 + 255) / 256;
    if (grid > 2048) grid = 2048;
    k_f2b<<<grid, 256, 0, st>>>(s, d, n4);
}

extern "C" void kernel_launch(void* const* d_in, const int* in_sizes, int n_in, void* d_out,
                              int out_size, void* d_ws, size_t ws_size, hipStream_t stream) {
    const float* f1 = (const float*)d_in[0];
    const int* adj_src = (const int*)d_in[1];
    const int* adj_dst = (const int*)d_in[2];
    const float* adj_val = (const float*)d_in[3];
    const int* edge_src = (const int*)d_in[4];
    const int* edge_dst = (const int*)d_in[5];
    const int* edge_index = (const int*)d_in[6];
    const int* edge_id = (const int*)d_in[7];
    const float* W_hyp = (const float*)d_in[8];
    const float* b_hyp = (const float*)d_in[9];
    const float* Wd = (const float*)d_in[10];
    const float* bd = (const float*)d_in[11];
    const float* Wg1 = (const float*)d_in[12];
    const float* bg1 = (const float*)d_in[13];
    const float* gamma = (const float*)d_in[14];
    const float* beta = (const float*)d_in[15];
    const float* Wg2 = (const float*)d_in[16];
    const float* bg2 = (const float*)d_in[17];
    const float* Wgate = (const float*)d_in[18];
    const float* bgate = (const float*)d_in[19];
    const float* Wint = (const float*)d_in[20];
    const float* bint = (const float*)d_in[21];
    const float* Wout = (const float*)d_in[22];
    const float* bout = (const float*)d_in[23];
    const float* Wf1 = (const float*)d_in[24];
    const float* bf1 = (const float*)d_in[25];
    const float* Wf2 = (const float*)d_in[26];
    const float* bf2 = (const float*)d_in[27];
    const float* Wf3 = (const float*)d_in[28];
    const float* bf3 = (const float*)d_in[29];
    float* outp = (float*)d_out;

    // ---- workspace bump allocator (~238 MB) ----
    char* base = (char*)d_ws;
    size_t off = 0;
    auto alloc = [&](size_t bytes) -> char* {
        char* p = base + off;
        off += (bytes + 255) & ~(size_t)255;
        return p;
    };
    u16* Whyp_b = (u16*)alloc((size_t)NCH * DH * D_INN * 2);
    u16* Wd_b   = (u16*)alloc((size_t)NCH * DH * DH * 2);
    u16* Wg1_b  = (u16*)alloc((size_t)NCH * DH * DH * 2);
    u16* Wg2_b  = (u16*)alloc((size_t)NCH * DH * DH * 2);
    u16* Wgate_b = (u16*)alloc((size_t)H3 * H3 * 2);
    u16* Wint_b  = (u16*)alloc((size_t)H3 * H3 * 2);
    u16* Wout_b  = (u16*)alloc((size_t)H3 * H3 * 2);
    u16* Wf1_b   = (u16*)alloc((size_t)1152 * H3 * 2);
    u16* Wf2_b   = (u16*)alloc((size_t)576 * 1152 * 2);
    u16* S_b = (u16*)alloc((size_t)NB * H3 * 2);
    u16* P_b = (u16*)alloc((size_t)NB * H3 * 2);
    const size_t NDB = (size_t)N_NODES * DH;       // per-channel elems
    u16* buf1 = (u16*)alloc(4 * NDB * 2);          // group ping
    u16* buf2 = (u16*)alloc(4 * NDB * 2);          // group pong
    u16* xhyp_b = (u16*)alloc((size_t)N_NODES * D_INN * 2);
    // merged CSR scratch (2G slices; G<=4): adj slices [0,G), edge slices [G,2G)
    int* cntC = (int*)alloc(8 * (size_t)N_NODES * 4);        // doubles as cursor
    int* rowptrC = (int*)alloc(8 * (size_t)(N_NODES + 1) * 4);
    int* psrcC = (int*)alloc(8 * (size_t)NE * 4);
    float* pvalC = (float*)alloc(4 * (size_t)NE * 4);
    float* xhn = (float*)alloc((size_t)N_NODES * 4);
    float* hb = (float*)alloc((size_t)NCH * DH * 4);
    float* hb2 = (float*)alloc(NCH * 4);
    float* csum = (float*)alloc((size_t)4 * DH * 4);
    float* csq = (float*)alloc((size_t)4 * DH * 4);
    // stage-C overlays (GNN buffers dead by then)
    u16* G_b = buf1;                 // 37.75 MB <= 40.96
    float* h2f = (float*)buf2;       // 18.87 MB <= 40.96

    const int EG = (NE + 255) / 256;

    conv_w(W_hyp, Whyp_b, (size_t)NCH * DH * D_INN, stream);
    conv_w(Wd, Wd_b, (size_t)NCH * DH * DH, stream);
    conv_w(Wg1, Wg1_b, (size_t)NCH * DH * DH, stream);
    conv_w(Wg2, Wg2_b, (size_t)NCH * DH * DH, stream);
    conv_w(Wgate, Wgate_b, (size_t)H3 * H3, stream);
    conv_w(Wint, Wint_b, (size_t)H3 * H3, stream);
    conv_w(Wout, Wout_b, (size_t)H3 * H3, stream);
    conv_w(Wf1, Wf1_b, (size_t)1152 * H3, stream);
    conv_w(Wf2, Wf2_b, (size_t)576 * 1152, stream);

    k_expmap_proj_in<<<N_NODES, 256, 0, stream>>>(f1, xhyp_b, xhn);
    k_hb<<<NCH, 256, 0, stream>>>(b_hyp, hb, hb2);
    k_pair0<<<NB, 256, 0, stream>>>(edge_index, edge_id, f1, S_b, P_b);

    const int g0s[2] = {0, 4};
    const int gns[2] = {4, 3};
    for (int gi = 0; gi < 2; ++gi) {
        const int g0 = g0s[gi], G = gns[gi];
        const size_t eoff = (size_t)g0 * NE;
        const int G2 = 2 * G;
        // --- merged CSR build (both graphs, one launch set) ---
        k_izero<<<(G2 * N_NODES + 255) / 256, 256, 0, stream>>>(cntC, G2 * N_NODES);
        k_hist2<<<dim3(EG, G2), 256, 0, stream>>>(adj_dst + eoff, edge_dst + eoff, cntC, G);
        k_scan<<<G2, 256, 0, stream>>>(cntC, rowptrC);
        k_place2<<<dim3(EG, G2), 256, 0, stream>>>(adj_src + eoff, adj_dst + eoff,
                                                   adj_val + eoff, edge_src + eoff,
                                                   edge_dst + eoff, cntC, psrcC, pvalC, G);
        // --- batched pipeline ---
        gemm_b(5, xhyp_b, Whyp_b + (size_t)g0 * DH * D_INN, nullptr, buf1, nullptr,
               N_NODES, DH, D_INN, G, 0, (size_t)DH * D_INN, NDB, 0, stream);
        k_rowfuse1<<<dim3(N_NODES / 4, G), 256, 0, stream>>>(buf1, xhn, hb + g0 * DH, hb2 + g0);
        k_gather_fuse2<<<dim3(N_NODES / 4, G), 256, 0, stream>>>(rowptrC, psrcC, pvalC,
                                                                 buf1, buf2);
        gemm_b(5, buf2, Wd_b + (size_t)g0 * DH * DH, bd + g0 * DH, buf1, nullptr,
               N_NODES, DH, DH, G, NDB, (size_t)DH * DH, NDB, DH, stream);
        k_gather_add<<<dim3(N_NODES / 4, G), 256, 0, stream>>>(
            rowptrC + (size_t)G * (N_NODES + 1), psrcC + (size_t)G * NE, buf1, buf2);
        gemm_b(5, buf2, Wg1_b + (size_t)g0 * DH * DH, bg1 + g0 * DH, buf1, nullptr,
               N_NODES, DH, DH, G, NDB, (size_t)DH * DH, NDB, DH, stream);
        k_zero<<<(2 * G * DH + 255) / 256, 256, 0, stream>>>(csum, G * DH);
        k_zero<<<(G * DH + 255) / 256, 256, 0, stream>>>(csq, G * DH);
        k_colstats<<<dim3(200, G), 256, 0, stream>>>(buf1, csum, csq);
        {
            int total4 = (int)(G * NDB / 4);
            int blocks = (total4 + 255) / 256;
            if (blocks > 2048) blocks = 2048;
            k_normtanh_v<<<blocks, 256, 0, stream>>>(buf1, csum, csq, gamma + g0 * DH,
                                                     beta + g0 * DH, total4);
        }
        gemm_b(5, buf1, Wg2_b + (size_t)g0 * DH * DH, bg2 + g0 * DH, buf2, nullptr,
               N_NODES, DH, DH, G, NDB, (size_t)DH * DH, NDB, DH, stream);
        k_gather_ch<<<dim3(NB / 4, G), 256, 0, stream>>>(edge_index, edge_id, buf2, S_b, P_b,
                                                         D_INN + g0 * DH);
    }

    // stage C (bf16 MFMA; gi->S_b, g->P_b, h1->G_b, h2->h2f)
    gemm_b(2, S_b, Wgate_b, bgate, G_b, nullptr, NB, H3, H3, 1, 0, 0, 0, 0, stream);
    gemm_b(4, P_b, Wint_b, bint, S_b, G_b, NB, H3, H3, 1, 0, 0, 0, 0, stream);
    gemm_b(5, S_b, Wout_b, bout, P_b, nullptr, NB, H3, H3, 1, 0, 0, 0, 0, stream);
    gemm_b(3, P_b, Wf1_b, bf1, G_b, nullptr, NB, 1152, H3, 1, 0, 0, 0, 0, stream);
    gemm_b(6, G_b, Wf2_b, bf2, h2f, nullptr, NB, 576, 1152, 1, 0, 0, 0, 0, stream);
    k_final<<<NB, 64, 0, stream>>>(h2f, Wf3, bf3, outp);
}

// Round 9
// 2121.784 us; speedup vs baseline: 1.5043x; 1.0124x over previous
//
#include <hip/hip_runtime.h>
#include <math.h>

#define N_NODES 20000
#define D_INN   512
#define DH      256
#define NCH     7
#define NE      320000
#define NE2     100000
#define NB      8192
#define H3      2304   // 512 + 7*256
#define MAXN    0.996f
#define LOG2E   1.44269504f

typedef unsigned short u16;
typedef __attribute__((ext_vector_type(8))) short bf16x8;
typedef __attribute__((ext_vector_type(4))) float f32x4;

__device__ __forceinline__ u16 f2b(float f) {    // RNE f32 -> bf16 bits
    unsigned int x = __float_as_uint(f);
    unsigned int r = (x + 0x7fffu + ((x >> 16) & 1u)) >> 16;
    return (u16)r;
}
__device__ __forceinline__ float b2f(u16 u) {
    return __uint_as_float(((unsigned int)u) << 16);
}
__device__ __forceinline__ float blo(unsigned int u) { return __uint_as_float(u << 16); }
__device__ __forceinline__ float bhi(unsigned int u) { return __uint_as_float(u & 0xffff0000u); }
__device__ __forceinline__ unsigned int pk2(float a, float b) {
    return (unsigned int)f2b(a) | ((unsigned int)f2b(b) << 16);
}

// ---- fast HW transcendentals (rel err ~1e-5, fine for bf16 tolerance) ----
__device__ __forceinline__ float rcp_f(float x) { return __builtin_amdgcn_rcpf(x); }
__device__ __forceinline__ float exp2_f(float x) { return __builtin_amdgcn_exp2f(x); }
__device__ __forceinline__ float log2_f(float x) { return __builtin_amdgcn_logf(x); }
__device__ __forceinline__ float tanh_fast(float x) {
    float xc = fminf(fmaxf(x, -15.f), 15.f);
    float t = exp2_f(xc * (2.f * LOG2E));
    return (t - 1.f) * rcp_f(t + 1.f);
}
__device__ __forceinline__ float artanh_fast(float x) {
    x = fminf(fmaxf(x, -1.0f + 1e-7f), 1.0f - 1e-7f);
    return 0.34657359f * log2_f((1.f + x) * rcp_f(1.f - x));
}
__device__ __forceinline__ float sigmoid_fast(float x) {
    return rcp_f(1.f + exp2_f(-x * LOG2E));
}

__device__ __forceinline__ float wave_sum(float v) {
    #pragma unroll
    for (int off = 32; off > 0; off >>= 1) v += __shfl_xor(v, off, 64);
    return v;
}

__device__ __forceinline__ float block_sum256(float v) {
    __shared__ float sred[4];
    #pragma unroll
    for (int off = 32; off > 0; off >>= 1) v += __shfl_down(v, off, 64);
    int lane = threadIdx.x & 63;
    int w = threadIdx.x >> 6;
    if (lane == 0) sred[w] = v;
    __syncthreads();
    float tot = sred[0] + sred[1] + sred[2] + sred[3];
    __syncthreads();
    return tot;
}

__global__ void k_zero(float* __restrict__ p, int n) {
    int i = blockIdx.x * 256 + threadIdx.x;
    if (i < n) p[i] = 0.0f;
}
__global__ void k_izero(int* __restrict__ p, int n) {
    int i = blockIdx.x * 256 + threadIdx.x;
    if (i < n) p[i] = 0;
}

__global__ void k_f2b(const float* __restrict__ s, u16* __restrict__ d, int n4) {
    int i = blockIdx.x * 256 + threadIdx.x;
    int stride = gridDim.x * 256;
    for (; i < n4; i += stride) {
        float4 v = ((const float4*)s)[i];
        uint2 o; o.x = pk2(v.x, v.y); o.y = pk2(v.z, v.w);
        ((uint2*)d)[i] = o;
    }
}

// Wd transpose -> bf16 (for Wc = Wg1 @ Wd via A@W^T kernel)
__global__ void k_twd(const float* __restrict__ Wd, u16* __restrict__ Wdt) {
    __shared__ float tile[16][17];
    int z = blockIdx.z;
    int bx = blockIdx.x * 16, by = blockIdx.y * 16;
    int tx = threadIdx.x & 15, ty = threadIdx.x >> 4;
    tile[ty][tx] = Wd[(size_t)z * DH * DH + (size_t)(by + ty) * DH + bx + tx];
    __syncthreads();
    Wdt[(size_t)z * DH * DH + (size_t)(bx + ty) * DH + by + tx] = f2b(tile[tx][ty]);
}

// cvec[z][j] = sum_k Wg1[z][j][k] * bd[z][k]   (f32)
__global__ void k_cvec(const float* __restrict__ Wg1, const float* __restrict__ bd,
                       float* __restrict__ cvec) {
    int z = blockIdx.x, j = threadIdx.x;
    const float* row = Wg1 + (size_t)z * DH * DH + (size_t)j * DH;
    const float* b = bd + (size_t)z * DH;
    float s = 0.f;
    for (int k = 0; k < DH; ++k) s = fmaf(row[k], b[k], s);
    cvec[(size_t)z * DH + j] = s;
}

// ===== merged CSR build: 2G z-slices (z<G: adj graph, z>=G: edge graph) =====
__global__ void k_hist2(const int* __restrict__ adjd, const int* __restrict__ edged,
                        int* __restrict__ cnt, int G) {
    int z = blockIdx.y;
    const int* dst = (z < G) ? adjd + (size_t)z * NE : edged + (size_t)(z - G) * NE;
    cnt += (size_t)z * N_NODES;
    int i = blockIdx.x * 256 + threadIdx.x;
    if (i < NE) atomicAdd(&cnt[dst[i]], 1);
}

// one block per slice; cnt becomes the cursor array in-place
__global__ void k_scan(int* __restrict__ cnt, int* __restrict__ rowptr) {
    int z = blockIdx.x;
    cnt += (size_t)z * N_NODES;
    rowptr += (size_t)z * (N_NODES + 1);
    __shared__ int part[256];
    int t = threadIdx.x;
    const int CH = (N_NODES + 255) / 256;
    int beg = t * CH;
    int end = beg + CH; if (end > N_NODES) end = N_NODES;
    int s = 0;
    for (int i = beg; i < end; ++i) s += cnt[i];
    part[t] = s;
    __syncthreads();
    for (int off = 1; off < 256; off <<= 1) {
        int v = (t >= off) ? part[t - off] : 0;
        __syncthreads();
        part[t] += v;
        __syncthreads();
    }
    int run = (t == 0) ? 0 : part[t - 1];
    for (int i = beg; i < end; ++i) {
        int c = cnt[i];
        rowptr[i] = run;
        cnt[i] = run;      // cursor init (in-place)
        run += c;
    }
    if (t == 255) rowptr[N_NODES] = part[255];
}

// place: adj slices write packed (src, val) uint2 (1 scatter store/edge);
// edge slices write int src.
__global__ void k_place2(const int* __restrict__ adjs, const int* __restrict__ adjd,
                         const float* __restrict__ adjv, const int* __restrict__ edges,
                         const int* __restrict__ edged, int* __restrict__ cursor,
                         uint2* __restrict__ padj, int* __restrict__ psrcE, int G) {
    int z = blockIdx.y;
    bool isadj = z < G;
    const int* src = isadj ? adjs + (size_t)z * NE : edges + (size_t)(z - G) * NE;
    const int* dst = isadj ? adjd + (size_t)z * NE : edged + (size_t)(z - G) * NE;
    cursor += (size_t)z * N_NODES;
    int i = blockIdx.x * 256 + threadIdx.x;
    if (i < NE) {
        int d = dst[i];
        int pos = atomicAdd(&cursor[d], 1);
        if (isadj) {
            uint2 p;
            p.x = (unsigned int)src[i];
            p.y = __float_as_uint(adjv[(size_t)z * NE + i]);
            padj[(size_t)z * NE + pos] = p;
        } else {
            psrcE[(size_t)(z - G) * NE + pos] = src[i];
        }
    }
}

// x_hyp = proj(expmap0(f1)) -> bf16; clamped row norm -> xhn (f32)
__global__ void k_expmap_proj_in(const float* __restrict__ f1,
                                 u16* __restrict__ xhyp, float* __restrict__ xhn) {
    int r = blockIdx.x, t = threadIdx.x;
    const float* u = f1 + (size_t)r * D_INN;
    float v0 = u[t], v1 = u[t + 256];
    float ss = block_sum256(v0 * v0 + v1 * v1);
    float nraw = sqrtf(ss);
    float n = fmaxf(nraw, 1e-15f);
    float c = tanh_fast(n) * rcp_f(n);
    float ny = c * nraw;
    float np = fmaxf(ny, 1e-15f);
    float s = (np > MAXN) ? MAXN * rcp_f(np) : 1.0f;
    float cs = c * s;
    u16* o = xhyp + (size_t)r * D_INN;
    o[t] = f2b(cs * v0);
    o[t + 256] = f2b(cs * v1);
    if (t == 0) xhn[r] = fminf(np, MAXN);
}

__global__ void k_hb(const float* __restrict__ b_hyp,
                     float* __restrict__ hb, float* __restrict__ hb2) {
    int i = blockIdx.x, t = threadIdx.x;
    float v = b_hyp[i * DH + t];
    float ss = block_sum256(v * v);
    float nraw = sqrtf(ss);
    float n = fmaxf(nraw, 1e-15f);
    float c = tanh_fast(n) * rcp_f(n);
    float ny = c * nraw;
    float np = fmaxf(ny, 1e-15f);
    float s = (np > MAXN) ? MAXN * rcp_f(np) : 1.0f;
    float hv = c * s * v;
    hb[i * DH + t] = hv;
    float s2 = block_sum256(hv * hv);
    if (t == 0) hb2[i] = s2;
}

// wave-per-node (4 nodes/block), lane = 4 feats via uint2; in-place bf16.
__global__ void k_rowfuse1(u16* __restrict__ T, const float* __restrict__ xhn,
                           const float* __restrict__ hb, const float* __restrict__ hb2) {
    int z = blockIdx.y;
    int n = blockIdx.x * 4 + (threadIdx.x >> 6);
    int lane = threadIdx.x & 63;
    u16* row = T + ((size_t)z * N_NODES + n) * DH;
    const float* hbz = hb + (size_t)z * DH;
    uint2 u = *(const uint2*)(row + lane * 4);
    float m0 = blo(u.x), m1 = bhi(u.x), m2 = blo(u.y), m3 = bhi(u.y);
    float ss = wave_sum(m0 * m0 + m1 * m1 + m2 * m2 + m3 * m3);
    float mxn_raw = sqrtf(ss);
    float mxn = fmaxf(mxn_raw, 1e-15f);
    float xn = xhn[n];
    float tt = tanh_fast(mxn * rcp_f(xn) * artanh_fast(xn));
    float coef = tt * rcp_f(mxn);
    float nres = coef * mxn_raw;
    float np = fmaxf(nres, 1e-15f);
    float s1 = (np > MAXN) ? MAXN * rcp_f(np) : 1.0f;
    float cs = coef * s1;
    float r0 = cs * m0, r1 = cs * m1, r2 = cs * m2, r3 = cs * m3;
    float n1 = fminf(np, MAXN);
    float4 hv = *(const float4*)(hbz + lane * 4);
    float xy = wave_sum(r0 * hv.x + r1 * hv.y + r2 * hv.z + r3 * hv.w);
    float x2 = n1 * n1, y2 = hb2[z];
    float ca = 1.0f + 2.0f * xy + y2;
    float cb = 1.0f - x2;
    float rden = rcp_f(fmaxf(1.0f + 2.0f * xy + x2 * y2, 1e-15f));
    float o0 = (ca * r0 + cb * hv.x) * rden;
    float o1 = (ca * r1 + cb * hv.y) * rden;
    float o2 = (ca * r2 + cb * hv.z) * rden;
    float o3 = (ca * r3 + cb * hv.w) * rden;
    float no2 = wave_sum(o0 * o0 + o1 * o1 + o2 * o2 + o3 * o3);
    float nop = fmaxf(sqrtf(no2), 1e-15f);
    float s2 = (nop > MAXN) ? MAXN * rcp_f(nop) : 1.0f;
    float n2 = fminf(nop, MAXN);
    float fin = artanh_fast(n2) * rcp_f(n2) * s2;
    uint2 o; o.x = pk2(fin * o0, fin * o1); o.y = pk2(fin * o2, fin * o3);
    *(uint2*)(row + lane * 4) = o;
}

// wave-per-node CSR gather (packed (src,val)) + fused rowfuse2 chain -> bf16 out
__global__ void k_gather_fuse2(const int* __restrict__ rowptr, const uint2* __restrict__ padj,
                               const u16* __restrict__ xt, u16* __restrict__ out) {
    int z = blockIdx.y;
    rowptr += (size_t)z * (N_NODES + 1);
    padj += (size_t)z * NE;
    xt += (size_t)z * N_NODES * DH;
    out += (size_t)z * N_NODES * DH;
    int n = blockIdx.x * 4 + (threadIdx.x >> 6);
    int lane = threadIdx.x & 63;
    int beg = rowptr[n], end = rowptr[n + 1];
    float a0 = 0.f, a1 = 0.f, a2 = 0.f, a3 = 0.f;
    for (int i = beg; i < end; ++i) {
        uint2 p = padj[i];
        float v = __uint_as_float(p.y);
        uint2 u = *(const uint2*)(xt + (size_t)p.x * DH + lane * 4);
        a0 = fmaf(v, blo(u.x), a0);
        a1 = fmaf(v, bhi(u.x), a1);
        a2 = fmaf(v, blo(u.y), a2);
        a3 = fmaf(v, bhi(u.y), a3);
    }
    float ss = wave_sum(a0 * a0 + a1 * a1 + a2 * a2 + a3 * a3);
    float nraw = sqrtf(ss);
    float n_ = fmaxf(nraw, 1e-15f);
    float c1 = tanh_fast(n_) * rcp_f(n_);
    float nh = c1 * nraw;
    float np1 = fmaxf(nh, 1e-15f);
    float s1 = (np1 > MAXN) ? MAXN * rcp_f(np1) : 1.0f;
    float n1 = fminf(np1, MAXN);
    float cu = artanh_fast(n1) * rcp_f(n1) * s1 * c1;
    float u0 = fmaxf(cu * a0, 0.f), u1 = fmaxf(cu * a1, 0.f);
    float u2 = fmaxf(cu * a2, 0.f), u3 = fmaxf(cu * a3, 0.f);
    float ss2 = wave_sum(u0 * u0 + u1 * u1 + u2 * u2 + u3 * u3);
    float n2raw = sqrtf(ss2);
    float n2 = fmaxf(n2raw, 1e-15f);
    float c3 = tanh_fast(n2) * rcp_f(n2);
    float ne = c3 * n2raw;
    float np3 = fmaxf(ne, 1e-15f);
    float s3 = (np3 > MAXN) ? MAXN * rcp_f(np3) : 1.0f;
    float n3 = fminf(np3, MAXN);
    float cf = artanh_fast(n3) * rcp_f(n3) * s3 * c3;
    uint2 o; o.x = pk2(cf * u0, cf * u1); o.y = pk2(cf * u2, cf * u3);
    *(uint2*)(out + (size_t)n * DH + lane * 4) = o;
}

// wave-per-node: out[n] = d[n] + sum_in d[src]; bf16 in/out
__global__ void k_gather_add(const int* __restrict__ rowptr, const int* __restrict__ psrc,
                             const u16* __restrict__ d, u16* __restrict__ out) {
    int z = blockIdx.y;
    rowptr += (size_t)z * (N_NODES + 1);
    psrc += (size_t)z * NE;
    d += (size_t)z * N_NODES * DH;
    out += (size_t)z * N_NODES * DH;
    int n = blockIdx.x * 4 + (threadIdx.x >> 6);
    int lane = threadIdx.x & 63;
    int beg = rowptr[n], end = rowptr[n + 1];
    uint2 u0v = *(const uint2*)(d + (size_t)n * DH + lane * 4);
    float a0 = blo(u0v.x), a1 = bhi(u0v.x), a2 = blo(u0v.y), a3 = bhi(u0v.y);
    for (int i = beg; i < end; ++i) {
        int s = psrc[i];
        uint2 u = *(const uint2*)(d + (size_t)s * DH + lane * 4);
        a0 += blo(u.x); a1 += bhi(u.x); a2 += blo(u.y); a3 += bhi(u.y);
    }
    uint2 o; o.x = pk2(a0, a1); o.y = pk2(a2, a3);
    *(uint2*)(out + (size_t)n * DH + lane * 4) = o;
}

// batched column stats from bf16
__global__ void k_colstats(const u16* __restrict__ zp,
                           float* __restrict__ csum, float* __restrict__ csq) {
    int z = blockIdx.y;
    zp += (size_t)z * N_NODES * DH;
    csum += (size_t)z * DH;
    csq += (size_t)z * DH;
    int t = threadIdx.x;
    int r0 = blockIdx.x * 100;
    float s = 0.0f, q = 0.0f;
    for (int r = r0; r < r0 + 100; ++r) {
        float v = b2f(zp[(size_t)r * DH + t]);
        s += v;
        q += v * v;
    }
    atomicAdd(&csum[t], s);
    atomicAdd(&csq[t], q);
}

// grid-stride uint2 batchnorm + tanh, in-place bf16 (total4 = G*N*DH/4)
__global__ void k_normtanh_v(u16* __restrict__ zp, const float* __restrict__ csum,
                             const float* __restrict__ csq, const float* __restrict__ gamma,
                             const float* __restrict__ beta, int total4) {
    const float inv_n = 1.0f / N_NODES;
    int i = blockIdx.x * 256 + threadIdx.x;
    int stride = gridDim.x * 256;
    for (; i < total4; i += stride) {
        int e0 = i * 4;
        int z = e0 / (N_NODES * DH);
        int j0 = e0 & (DH - 1);
        int zb = z * DH + j0;
        uint2 u = ((uint2*)zp)[i];
        float v[4] = {blo(u.x), bhi(u.x), blo(u.y), bhi(u.y)};
        #pragma unroll
        for (int k = 0; k < 4; ++k) {
            float mu = csum[zb + k] * inv_n;
            float var = csq[zb + k] * inv_n - mu * mu;
            float inv = __builtin_amdgcn_rsqf(var + 1e-5f);
            v[k] = tanh_fast((v[k] - mu) * inv * gamma[zb + k] + beta[zb + k]);
        }
        uint2 o; o.x = pk2(v[0], v[1]); o.y = pk2(v[2], v[3]);
        ((uint2*)zp)[i] = o;
    }
}

// f1 slice of S,P (cols 0..511): thread t -> 2 cols via float2, packed u32 store
__global__ void k_pair0(const int* __restrict__ ei, const int* __restrict__ eid,
                        const float* __restrict__ f1, u16* __restrict__ S,
                        u16* __restrict__ P) {
    int b = blockIdx.x, t = threadIdx.x;
    int e = eid[b];
    int n0 = ei[e], n1 = ei[NE2 + e];
    float2 a = *(const float2*)(f1 + (size_t)n0 * D_INN + t * 2);
    float2 c = *(const float2*)(f1 + (size_t)n1 * D_INN + t * 2);
    ((unsigned int*)(S + (size_t)b * H3))[t] = pk2(a.x + c.x, a.y + c.y);
    ((unsigned int*)(P + (size_t)b * H3))[t] = pk2(a.x * c.x, a.y * c.y);
}

// batched channel slice of S,P from z_ch; 4 edges/block, uint2 lanes
__global__ void k_gather_ch(const int* __restrict__ ei, const int* __restrict__ eid,
                            const u16* __restrict__ zch, u16* __restrict__ S,
                            u16* __restrict__ P, int col0base) {
    int z = blockIdx.y;
    const u16* zp = zch + (size_t)z * N_NODES * DH;
    int col0 = col0base + z * DH;
    int b = blockIdx.x * 4 + (threadIdx.x >> 6);
    int lane = threadIdx.x & 63;
    int e = eid[b];
    int n0 = ei[e], n1 = ei[NE2 + e];
    uint2 ua = *(const uint2*)(zp + (size_t)n0 * DH + lane * 4);
    uint2 ub = *(const uint2*)(zp + (size_t)n1 * DH + lane * 4);
    float a0 = blo(ua.x), a1 = bhi(ua.x), a2 = blo(ua.y), a3 = bhi(ua.y);
    float c0 = blo(ub.x), c1 = bhi(ub.x), c2 = blo(ub.y), c3 = bhi(ub.y);
    uint2 so; so.x = pk2(a0 + c0, a1 + c1); so.y = pk2(a2 + c2, a3 + c3);
    uint2 po; po.x = pk2(a0 * c0, a1 * c1); po.y = pk2(a2 * c2, a3 * c3);
    *(uint2*)(S + (size_t)b * H3 + col0 + lane * 4) = so;
    *(uint2*)(P + (size_t)b * H3 + col0 + lane * 4) = po;
}

__global__ void k_final(const float* __restrict__ h2, const float* __restrict__ Wf3,
                        const float* __restrict__ bf3, float* __restrict__ out) {
    int r = blockIdx.x, t = threadIdx.x;
    const float* hr = h2 + (size_t)r * 576;
    float acc[7] = {0, 0, 0, 0, 0, 0, 0};
    for (int cb = t; cb < 576; cb += 64) {
        float h = hr[cb];
        #pragma unroll
        for (int o = 0; o < 7; ++o) acc[o] = fmaf(h, Wf3[o * 576 + cb], acc[o]);
    }
    #pragma unroll
    for (int o = 0; o < 7; ++o) {
        #pragma unroll
        for (int off = 32; off > 0; off >>= 1) acc[o] += __shfl_down(acc[o], off, 64);
    }
    if (t == 0) {
        #pragma unroll
        for (int o = 0; o < 7; ++o) out[(size_t)r * 7 + o] = acc[o] + bf3[o];
    }
}

// ===== bf16 MFMA GEMM (batched over blockIdx.z with strides).
// Reg-staged, LDS 16B-slot swizzle; XCD-aware bijective block swizzle per z.
// EP: 2=sigmoid->bf16, 3=relu->bf16, 4=aux*relu->bf16, 5=bf16, 6=relu->f32,
//     7=bf16 with bias + (1+indeg[row])*cvec[col]  (rpe = edge rowptr base)
template <int EP>
__global__ __launch_bounds__(256, 2) void k_gemm_mfma(
    const u16* __restrict__ A, const u16* __restrict__ W,
    const float* __restrict__ bias, void* __restrict__ outv,
    const u16* __restrict__ aux, const int* __restrict__ rpe,
    const float* __restrict__ cvec, int M, int N, int K,
    size_t sA, size_t sW, size_t sC, int sBias) {
    __shared__ short As[4096];   // 128x32 bf16
    __shared__ short Ws[4096];
    const int z = blockIdx.z;
    A += (size_t)z * sA;
    W += (size_t)z * sW;
    const size_t zC = (size_t)z * sC;
    const int* rp = (EP == 7) ? rpe + (size_t)z * (N_NODES + 1) : nullptr;
    const float* cv = (EP == 7) ? cvec + (size_t)z * DH : nullptr;
    // XCD bijective swizzle within this z-slice
    const int gx = gridDim.x;
    const int nwg = gx * gridDim.y;
    const int orig = blockIdx.y * gx + blockIdx.x;
    const int q = nwg >> 3, r8 = nwg & 7, xcd = orig & 7;
    const int wg = (xcd < r8 ? xcd * (q + 1) : r8 * (q + 1) + (xcd - r8) * q) + (orig >> 3);
    const int row0 = (wg / gx) * 128, col0 = (wg % gx) * 128;
    const int t = threadIdx.x;
    const int lane = t & 63;
    const int w = t >> 6;
    const int wr = w >> 1, wc = w & 1;
    const int rkc = lane >> 4, rr = lane & 15;
    const int rdoff = (rkc * 16 + ((rr + 2 * rkc) & 15)) * 8;  // shorts
    f32x4 acc[4][4] = {};
    for (int k0 = 0; k0 < K; k0 += 32) {
        #pragma unroll
        for (int p = 0; p < 2; ++p) {
            int i = t + p * 256;               // 0..511
            int row = i >> 2, kc = i & 3;
            int gr = row0 + row; gr = (gr < M) ? gr : (M - 1);
            int gc = col0 + row; gc = (gc < N) ? gc : (N - 1);
            uint4 va = *(const uint4*)(A + (size_t)gr * K + k0 + kc * 8);
            uint4 vw = *(const uint4*)(W + (size_t)gc * K + k0 + kc * 8);
            int off = (row >> 4) * 512 + (kc * 16 + (((row & 15) + 2 * kc) & 15)) * 8;
            *(uint4*)(As + off) = va;
            *(uint4*)(Ws + off) = vw;
        }
        __syncthreads();
        bf16x8 af[4], bfr[4];
        #pragma unroll
        for (int m = 0; m < 4; ++m)
            af[m] = *(const bf16x8*)(As + (wr * 4 + m) * 512 + rdoff);
        #pragma unroll
        for (int n = 0; n < 4; ++n)
            bfr[n] = *(const bf16x8*)(Ws + (wc * 4 + n) * 512 + rdoff);
        #pragma unroll
        for (int m = 0; m < 4; ++m)
            #pragma unroll
            for (int n = 0; n < 4; ++n)
                acc[m][n] = __builtin_amdgcn_mfma_f32_16x16x32_bf16(af[m], bfr[n], acc[m][n], 0, 0, 0);
        __syncthreads();
    }
    const int cl = lane & 15, rh = (lane >> 4) * 4;
    #pragma unroll
    for (int m = 0; m < 4; ++m) {
        float indf[4];
        if (EP == 7) {
            #pragma unroll
            for (int r = 0; r < 4; ++r) {
                int row = row0 + wr * 64 + m * 16 + rh + r;
                if (row >= M) row = M - 1;
                indf[r] = 1.0f + (float)(rp[row + 1] - rp[row]);
            }
        }
        #pragma unroll
        for (int n = 0; n < 4; ++n) {
            int col = col0 + wc * 64 + n * 16 + cl;
            if (col >= N) continue;
            float bv = bias ? bias[z * sBias + col] : 0.0f;
            float cvc = (EP == 7) ? cv[col] : 0.0f;
            #pragma unroll
            for (int r = 0; r < 4; ++r) {
                int row = row0 + wr * 64 + m * 16 + rh + r;
                if (row >= M) continue;
                float v = acc[m][n][r] + bv;
                size_t idx = zC + (size_t)row * N + col;
                if (EP == 2) ((u16*)outv)[idx] = f2b(sigmoid_fast(v));
                if (EP == 3) ((u16*)outv)[idx] = f2b(fmaxf(v, 0.0f));
                if (EP == 4) { float g = b2f(aux[idx]); ((u16*)outv)[idx] = f2b(g * fmaxf(v, 0.0f)); }
                if (EP == 5) ((u16*)outv)[idx] = f2b(v);
                if (EP == 6) ((float*)outv)[idx] = fmaxf(v, 0.0f);
                if (EP == 7) ((u16*)outv)[idx] = f2b(v + indf[r] * cvc);
            }
        }
    }
}

static inline void gemm_b(int ep, const u16* A, const u16* W, const float* bias, void* out,
                          const u16* aux, const int* rpe, const float* cvec,
                          int M, int N, int K, int Z,
                          size_t sA, size_t sW, size_t sC, int sBias, hipStream_t st) {
    dim3 g((N + 127) / 128, (M + 127) / 128, Z);
    switch (ep) {
        case 2: k_gemm_mfma<2><<<g, 256, 0, st>>>(A, W, bias, out, aux, rpe, cvec, M, N, K, sA, sW, sC, sBias); break;
        case 3: k_gemm_mfma<3><<<g, 256, 0, st>>>(A, W, bias, out, aux, rpe, cvec, M, N, K, sA, sW, sC, sBias); break;
        case 4: k_gemm_mfma<4><<<g, 256, 0, st>>>(A, W, bias, out, aux, rpe, cvec, M, N, K, sA, sW, sC, sBias); break;
        case 5: k_gemm_mfma<5><<<g, 256, 0, st>>>(A, W, bias, out, aux, rpe, cvec, M, N, K, sA, sW, sC, sBias); break;
        case 6: k_gemm_mfma<6><<<g, 256, 0, st>>>(A, W, bias, out, aux, rpe, cvec, M, N, K, sA, sW, sC, sBias); break;
        case 7: k_gemm_mfma<7><<<g, 256, 0, st>>>(A, W, bias, out, aux, rpe, cvec, M, N, K, sA, sW, sC, sBias); break;
    }
}

static inline void conv_w(const float* s, u16* d, size_t n, hipStream_t st) {
    int n4 = (int)(n / 4);
    int grid = (n4 + 255) / 256;
    if (grid > 2048) grid = 2048;
    k_f2b<<<grid, 256, 0, st>>>(s, d, n4);
}

extern "C" void kernel_launch(void* const* d_in, const int* in_sizes, int n_in, void* d_out,
                              int out_size, void* d_ws, size_t ws_size, hipStream_t stream) {
    const float* f1 = (const float*)d_in[0];
    const int* adj_src = (const int*)d_in[1];
    const int* adj_dst = (const int*)d_in[2];
    const float* adj_val = (const float*)d_in[3];
    const int* edge_src = (const int*)d_in[4];
    const int* edge_dst = (const int*)d_in[5];
    const int* edge_index = (const int*)d_in[6];
    const int* edge_id = (const int*)d_in[7];
    const float* W_hyp = (const float*)d_in[8];
    const float* b_hyp = (const float*)d_in[9];
    const float* Wd = (const float*)d_in[10];
    const float* bd = (const float*)d_in[11];
    const float* Wg1 = (const float*)d_in[12];
    const float* bg1 = (const float*)d_in[13];
    const float* gamma = (const float*)d_in[14];
    const float* beta = (const float*)d_in[15];
    const float* Wg2 = (const float*)d_in[16];
    const float* bg2 = (const float*)d_in[17];
    const float* Wgate = (const float*)d_in[18];
    const float* bgate = (const float*)d_in[19];
    const float* Wint = (const float*)d_in[20];
    const float* bint = (const float*)d_in[21];
    const float* Wout = (const float*)d_in[22];
    const float* bout = (const float*)d_in[23];
    const float* Wf1 = (const float*)d_in[24];
    const float* bf1 = (const float*)d_in[25];
    const float* Wf2 = (const float*)d_in[26];
    const float* bf2 = (const float*)d_in[27];
    const float* Wf3 = (const float*)d_in[28];
    const float* bf3 = (const float*)d_in[29];
    float* outp = (float*)d_out;

    // ---- workspace bump allocator (~240 MB) ----
    char* base = (char*)d_ws;
    size_t off = 0;
    auto alloc = [&](size_t bytes) -> char* {
        char* p = base + off;
        off += (bytes + 255) & ~(size_t)255;
        return p;
    };
    u16* Whyp_b = (u16*)alloc((size_t)NCH * DH * D_INN * 2);
    u16* Wdt_b  = (u16*)alloc((size_t)NCH * DH * DH * 2);   // Wd^T bf16
    u16* Wc_b   = (u16*)alloc((size_t)NCH * DH * DH * 2);   // Wg1 @ Wd
    u16* Wg1_b  = (u16*)alloc((size_t)NCH * DH * DH * 2);
    u16* Wg2_b  = (u16*)alloc((size_t)NCH * DH * DH * 2);
    u16* Wgate_b = (u16*)alloc((size_t)H3 * H3 * 2);
    u16* Wint_b  = (u16*)alloc((size_t)H3 * H3 * 2);
    u16* Wout_b  = (u16*)alloc((size_t)H3 * H3 * 2);
    u16* Wf1_b   = (u16*)alloc((size_t)1152 * H3 * 2);
    u16* Wf2_b   = (u16*)alloc((size_t)576 * 1152 * 2);
    u16* S_b = (u16*)alloc((size_t)NB * H3 * 2);
    u16* P_b = (u16*)alloc((size_t)NB * H3 * 2);
    const size_t NDB = (size_t)N_NODES * DH;       // per-channel elems
    u16* buf1 = (u16*)alloc(4 * NDB * 2);          // group ping
    u16* buf2 = (u16*)alloc(4 * NDB * 2);          // group pong
    u16* xhyp_b = (u16*)alloc((size_t)N_NODES * D_INN * 2);
    // merged CSR scratch (2G slices; G<=4): adj slices [0,G), edge slices [G,2G)
    int* cntC = (int*)alloc(8 * (size_t)N_NODES * 4);        // doubles as cursor
    int* rowptrC = (int*)alloc(8 * (size_t)(N_NODES + 1) * 4);
    uint2* padjC = (uint2*)alloc(4 * (size_t)NE * 8);        // packed (src,val)
    int* psrcE = (int*)alloc(4 * (size_t)NE * 4);
    float* xhn = (float*)alloc((size_t)N_NODES * 4);
    float* hb = (float*)alloc((size_t)NCH * DH * 4);
    float* hb2 = (float*)alloc(NCH * 4);
    float* csum = (float*)alloc((size_t)4 * DH * 4);
    float* csq = (float*)alloc((size_t)4 * DH * 4);
    float* cvec_d = (float*)alloc((size_t)NCH * DH * 4);
    // stage-C overlays (GNN buffers dead by then)
    u16* G_b = buf1;                 // 37.75 MB <= 40.96
    float* h2f = (float*)buf2;       // 18.87 MB <= 40.96

    const int EG = (NE + 255) / 256;

    conv_w(W_hyp, Whyp_b, (size_t)NCH * DH * D_INN, stream);
    conv_w(Wg1, Wg1_b, (size_t)NCH * DH * DH, stream);
    conv_w(Wg2, Wg2_b, (size_t)NCH * DH * DH, stream);
    conv_w(Wgate, Wgate_b, (size_t)H3 * H3, stream);
    conv_w(Wint, Wint_b, (size_t)H3 * H3, stream);
    conv_w(Wout, Wout_b, (size_t)H3 * H3, stream);
    conv_w(Wf1, Wf1_b, (size_t)1152 * H3, stream);
    conv_w(Wf2, Wf2_b, (size_t)576 * 1152, stream);
    // Wc = Wg1 @ Wd (via Wd^T), cvec = Wg1 @ bd
    k_twd<<<dim3(16, 16, NCH), 256, 0, stream>>>(Wd, Wdt_b);
    gemm_b(5, Wg1_b, Wdt_b, nullptr, Wc_b, nullptr, nullptr, nullptr,
           DH, DH, DH, NCH, (size_t)DH * DH, (size_t)DH * DH, (size_t)DH * DH, 0, stream);
    k_cvec<<<NCH, 256, 0, stream>>>(Wg1, bd, cvec_d);

    k_expmap_proj_in<<<N_NODES, 256, 0, stream>>>(f1, xhyp_b, xhn);
    k_hb<<<NCH, 256, 0, stream>>>(b_hyp, hb, hb2);
    k_pair0<<<NB, 256, 0, stream>>>(edge_index, edge_id, f1, S_b, P_b);

    const int g0s[2] = {0, 4};
    const int gns[2] = {4, 3};
    for (int gi = 0; gi < 2; ++gi) {
        const int g0 = g0s[gi], G = gns[gi];
        const size_t eoff = (size_t)g0 * NE;
        const int G2 = 2 * G;
        const int* rpE = rowptrC + (size_t)G * (N_NODES + 1);
        // --- merged CSR build (both graphs, one launch set) ---
        k_izero<<<(G2 * N_NODES + 255) / 256, 256, 0, stream>>>(cntC, G2 * N_NODES);
        k_hist2<<<dim3(EG, G2), 256, 0, stream>>>(adj_dst + eoff, edge_dst + eoff, cntC, G);
        k_scan<<<G2, 256, 0, stream>>>(cntC, rowptrC);
        k_place2<<<dim3(EG, G2), 256, 0, stream>>>(adj_src + eoff, adj_dst + eoff,
                                                   adj_val + eoff, edge_src + eoff,
                                                   edge_dst + eoff, cntC, padjC, psrcE, G);
        // --- batched pipeline ---
        gemm_b(5, xhyp_b, Whyp_b + (size_t)g0 * DH * D_INN, nullptr, buf1, nullptr,
               nullptr, nullptr, N_NODES, DH, D_INN, G, 0, (size_t)DH * D_INN, NDB, 0, stream);
        k_rowfuse1<<<dim3(N_NODES / 4, G), 256, 0, stream>>>(buf1, xhn, hb + g0 * DH, hb2 + g0);
        k_gather_fuse2<<<dim3(N_NODES / 4, G), 256, 0, stream>>>(rowptrC, padjC, buf1, buf2);
        // ug = (I + S_e) u
        k_gather_add<<<dim3(N_NODES / 4, G), 256, 0, stream>>>(rpE, psrcE, buf2, buf1);
        // z = ug @ Wc^T + (1+indeg)*cvec + bg1   (Wd GEMM fused away)
        gemm_b(7, buf1, Wc_b + (size_t)g0 * DH * DH, bg1 + g0 * DH, buf2, nullptr,
               rpE, cvec_d + (size_t)g0 * DH, N_NODES, DH, DH, G,
               NDB, (size_t)DH * DH, NDB, DH, stream);
        k_zero<<<(G * DH + 255) / 256, 256, 0, stream>>>(csum, G * DH);
        k_zero<<<(G * DH + 255) / 256, 256, 0, stream>>>(csq, G * DH);
        k_colstats<<<dim3(200, G), 256, 0, stream>>>(buf2, csum, csq);
        {
            int total4 = (int)(G * NDB / 4);
            int blocks = (total4 + 255) / 256;
            if (blocks > 2048) blocks = 2048;
            k_normtanh_v<<<blocks, 256, 0, stream>>>(buf2, csum, csq, gamma + g0 * DH,
                                                     beta + g0 * DH, total4);
        }
        gemm_b(5, buf2, Wg2_b + (size_t)g0 * DH * DH, bg2 + g0 * DH, buf1, nullptr,
               nullptr, nullptr, N_NODES, DH, DH, G, NDB, (size_t)DH * DH, NDB, DH, stream);
        k_gather_ch<<<dim3(NB / 4, G), 256, 0, stream>>>(edge_index, edge_id, buf1, S_b, P_b,
                                                         D_INN + g0 * DH);
    }

    // stage C (bf16 MFMA; gate->G_b, gi->S_b, g->P_b, h1->G_b, h2->h2f)
    gemm_b(2, S_b, Wgate_b, bgate, G_b, nullptr, nullptr, nullptr, NB, H3, H3, 1, 0, 0, 0, 0, stream);
    gemm_b(4, P_b, Wint_b, bint, S_b, G_b, nullptr, nullptr, NB, H3, H3, 1, 0, 0, 0, 0, stream);
    gemm_b(5, S_b, Wout_b, bout, P_b, nullptr, nullptr, nullptr, NB, H3, H3, 1, 0, 0, 0, 0, stream);
    gemm_b(3, P_b, Wf1_b, bf1, G_b, nullptr, nullptr, nullptr, NB, 1152, H3, 1, 0, 0, 0, 0, stream);
    gemm_b(6, G_b, Wf2_b, bf2, h2f, nullptr, nullptr, nullptr, NB, 576, 1152, 1, 0, 0, 0, 0, stream);
    k_final<<<NB, 64, 0, stream>>>(h2f, Wf3, bf3, outp);
}

// Round 10
// 2087.802 us; speedup vs baseline: 1.5288x; 1.0163x over previous
//
#include <hip/hip_runtime.h>
#include <math.h>

#define N_NODES 20000
#define D_INN   512
#define DH      256
#define NCH     7
#define NE      320000
#define NE2     100000
#define NB      8192
#define H3      2304   // 512 + 7*256
#define MAXN    0.996f
#define LOG2E   1.44269504f

typedef unsigned short u16;
typedef __attribute__((ext_vector_type(8))) short bf16x8;
typedef __attribute__((ext_vector_type(4))) float f32x4;

__device__ __forceinline__ u16 f2b(float f) {    // RNE f32 -> bf16 bits
    unsigned int x = __float_as_uint(f);
    unsigned int r = (x + 0x7fffu + ((x >> 16) & 1u)) >> 16;
    return (u16)r;
}
__device__ __forceinline__ float b2f(u16 u) {
    return __uint_as_float(((unsigned int)u) << 16);
}
__device__ __forceinline__ float blo(unsigned int u) { return __uint_as_float(u << 16); }
__device__ __forceinline__ float bhi(unsigned int u) { return __uint_as_float(u & 0xffff0000u); }
__device__ __forceinline__ unsigned int pk2(float a, float b) {
    return (unsigned int)f2b(a) | ((unsigned int)f2b(b) << 16);
}

// ---- fast HW transcendentals (rel err ~1e-5, fine for bf16 tolerance) ----
__device__ __forceinline__ float rcp_f(float x) { return __builtin_amdgcn_rcpf(x); }
__device__ __forceinline__ float exp2_f(float x) { return __builtin_amdgcn_exp2f(x); }
__device__ __forceinline__ float log2_f(float x) { return __builtin_amdgcn_logf(x); }
__device__ __forceinline__ float tanh_fast(float x) {
    float xc = fminf(fmaxf(x, -15.f), 15.f);
    float t = exp2_f(xc * (2.f * LOG2E));
    return (t - 1.f) * rcp_f(t + 1.f);
}
__device__ __forceinline__ float artanh_fast(float x) {
    x = fminf(fmaxf(x, -1.0f + 1e-7f), 1.0f - 1e-7f);
    return 0.34657359f * log2_f((1.f + x) * rcp_f(1.f - x));
}
__device__ __forceinline__ float sigmoid_fast(float x) {
    return rcp_f(1.f + exp2_f(-x * LOG2E));
}

__device__ __forceinline__ float wave_sum(float v) {
    #pragma unroll
    for (int off = 32; off > 0; off >>= 1) v += __shfl_xor(v, off, 64);
    return v;
}

__device__ __forceinline__ float block_sum256(float v) {
    __shared__ float sred[4];
    #pragma unroll
    for (int off = 32; off > 0; off >>= 1) v += __shfl_down(v, off, 64);
    int lane = threadIdx.x & 63;
    int w = threadIdx.x >> 6;
    if (lane == 0) sred[w] = v;
    __syncthreads();
    float tot = sred[0] + sred[1] + sred[2] + sred[3];
    __syncthreads();
    return tot;
}

__global__ void k_zero(float* __restrict__ p, int n) {
    int i = blockIdx.x * 256 + threadIdx.x;
    if (i < n) p[i] = 0.0f;
}
__global__ void k_izero(int* __restrict__ p, int n) {
    int i = blockIdx.x * 256 + threadIdx.x;
    if (i < n) p[i] = 0;
}

__global__ void k_f2b(const float* __restrict__ s, u16* __restrict__ d, int n4) {
    int i = blockIdx.x * 256 + threadIdx.x;
    int stride = gridDim.x * 256;
    for (; i < n4; i += stride) {
        float4 v = ((const float4*)s)[i];
        uint2 o; o.x = pk2(v.x, v.y); o.y = pk2(v.z, v.w);
        ((uint2*)d)[i] = o;
    }
}

// Wd transpose -> bf16 (for Wc = Wg1 @ Wd via A@W^T kernel)
__global__ void k_twd(const float* __restrict__ Wd, u16* __restrict__ Wdt) {
    __shared__ float tile[16][17];
    int z = blockIdx.z;
    int bx = blockIdx.x * 16, by = blockIdx.y * 16;
    int tx = threadIdx.x & 15, ty = threadIdx.x >> 4;
    tile[ty][tx] = Wd[(size_t)z * DH * DH + (size_t)(by + ty) * DH + bx + tx];
    __syncthreads();
    Wdt[(size_t)z * DH * DH + (size_t)(bx + ty) * DH + by + tx] = f2b(tile[tx][ty]);
}

// cvec[z][j] = sum_k Wg1[z][j][k] * bd[z][k]   (f32)
__global__ void k_cvec(const float* __restrict__ Wg1, const float* __restrict__ bd,
                       float* __restrict__ cvec) {
    int z = blockIdx.x, j = threadIdx.x;
    const float* row = Wg1 + (size_t)z * DH * DH + (size_t)j * DH;
    const float* b = bd + (size_t)z * DH;
    float s = 0.f;
    for (int k = 0; k < DH; ++k) s = fmaf(row[k], b[k], s);
    cvec[(size_t)z * DH + j] = s;
}

// ===== merged CSR build: 2G z-slices (z<G: adj graph, z>=G: edge graph) =====
__global__ void k_hist2(const int* __restrict__ adjd, const int* __restrict__ edged,
                        int* __restrict__ cnt, int G) {
    int z = blockIdx.y;
    const int* dst = (z < G) ? adjd + (size_t)z * NE : edged + (size_t)(z - G) * NE;
    cnt += (size_t)z * N_NODES;
    int i = blockIdx.x * 256 + threadIdx.x;
    if (i < NE) atomicAdd(&cnt[dst[i]], 1);
}

// one block per slice; cnt becomes the cursor array in-place
__global__ void k_scan(int* __restrict__ cnt, int* __restrict__ rowptr) {
    int z = blockIdx.x;
    cnt += (size_t)z * N_NODES;
    rowptr += (size_t)z * (N_NODES + 1);
    __shared__ int part[256];
    int t = threadIdx.x;
    const int CH = (N_NODES + 255) / 256;
    int beg = t * CH;
    int end = beg + CH; if (end > N_NODES) end = N_NODES;
    int s = 0;
    for (int i = beg; i < end; ++i) s += cnt[i];
    part[t] = s;
    __syncthreads();
    for (int off = 1; off < 256; off <<= 1) {
        int v = (t >= off) ? part[t - off] : 0;
        __syncthreads();
        part[t] += v;
        __syncthreads();
    }
    int run = (t == 0) ? 0 : part[t - 1];
    for (int i = beg; i < end; ++i) {
        int c = cnt[i];
        rowptr[i] = run;
        cnt[i] = run;      // cursor init (in-place)
        run += c;
    }
    if (t == 255) rowptr[N_NODES] = part[255];
}

// place: adj slices write packed (src, val) uint2 (1 scatter store/edge);
// edge slices write int src.
__global__ void k_place2(const int* __restrict__ adjs, const int* __restrict__ adjd,
                         const float* __restrict__ adjv, const int* __restrict__ edges,
                         const int* __restrict__ edged, int* __restrict__ cursor,
                         uint2* __restrict__ padj, int* __restrict__ psrcE, int G) {
    int z = blockIdx.y;
    bool isadj = z < G;
    const int* src = isadj ? adjs + (size_t)z * NE : edges + (size_t)(z - G) * NE;
    const int* dst = isadj ? adjd + (size_t)z * NE : edged + (size_t)(z - G) * NE;
    cursor += (size_t)z * N_NODES;
    int i = blockIdx.x * 256 + threadIdx.x;
    if (i < NE) {
        int d = dst[i];
        int pos = atomicAdd(&cursor[d], 1);
        if (isadj) {
            uint2 p;
            p.x = (unsigned int)src[i];
            p.y = __float_as_uint(adjv[(size_t)z * NE + i]);
            padj[(size_t)z * NE + pos] = p;
        } else {
            psrcE[(size_t)(z - G) * NE + pos] = src[i];
        }
    }
}

// x_hyp = proj(expmap0(f1)) -> bf16; clamped row norm -> xhn (f32)
__global__ void k_expmap_proj_in(const float* __restrict__ f1,
                                 u16* __restrict__ xhyp, float* __restrict__ xhn) {
    int r = blockIdx.x, t = threadIdx.x;
    const float* u = f1 + (size_t)r * D_INN;
    float v0 = u[t], v1 = u[t + 256];
    float ss = block_sum256(v0 * v0 + v1 * v1);
    float nraw = sqrtf(ss);
    float n = fmaxf(nraw, 1e-15f);
    float c = tanh_fast(n) * rcp_f(n);
    float ny = c * nraw;
    float np = fmaxf(ny, 1e-15f);
    float s = (np > MAXN) ? MAXN * rcp_f(np) : 1.0f;
    float cs = c * s;
    u16* o = xhyp + (size_t)r * D_INN;
    o[t] = f2b(cs * v0);
    o[t + 256] = f2b(cs * v1);
    if (t == 0) xhn[r] = fminf(np, MAXN);
}

__global__ void k_hb(const float* __restrict__ b_hyp,
                     float* __restrict__ hb, float* __restrict__ hb2) {
    int i = blockIdx.x, t = threadIdx.x;
    float v = b_hyp[i * DH + t];
    float ss = block_sum256(v * v);
    float nraw = sqrtf(ss);
    float n = fmaxf(nraw, 1e-15f);
    float c = tanh_fast(n) * rcp_f(n);
    float ny = c * nraw;
    float np = fmaxf(ny, 1e-15f);
    float s = (np > MAXN) ? MAXN * rcp_f(np) : 1.0f;
    float hv = c * s * v;
    hb[i * DH + t] = hv;
    float s2 = block_sum256(hv * hv);
    if (t == 0) hb2[i] = s2;
}

// wave-per-node (4 nodes/block), lane = 4 feats via uint2; in-place bf16.
__global__ void k_rowfuse1(u16* __restrict__ T, const float* __restrict__ xhn,
                           const float* __restrict__ hb, const float* __restrict__ hb2) {
    int z = blockIdx.y;
    int n = blockIdx.x * 4 + (threadIdx.x >> 6);
    int lane = threadIdx.x & 63;
    u16* row = T + ((size_t)z * N_NODES + n) * DH;
    const float* hbz = hb + (size_t)z * DH;
    uint2 u = *(const uint2*)(row + lane * 4);
    float m0 = blo(u.x), m1 = bhi(u.x), m2 = blo(u.y), m3 = bhi(u.y);
    float ss = wave_sum(m0 * m0 + m1 * m1 + m2 * m2 + m3 * m3);
    float mxn_raw = sqrtf(ss);
    float mxn = fmaxf(mxn_raw, 1e-15f);
    float xn = xhn[n];
    float tt = tanh_fast(mxn * rcp_f(xn) * artanh_fast(xn));
    float coef = tt * rcp_f(mxn);
    float nres = coef * mxn_raw;
    float np = fmaxf(nres, 1e-15f);
    float s1 = (np > MAXN) ? MAXN * rcp_f(np) : 1.0f;
    float cs = coef * s1;
    float r0 = cs * m0, r1 = cs * m1, r2 = cs * m2, r3 = cs * m3;
    float n1 = fminf(np, MAXN);
    float4 hv = *(const float4*)(hbz + lane * 4);
    float xy = wave_sum(r0 * hv.x + r1 * hv.y + r2 * hv.z + r3 * hv.w);
    float x2 = n1 * n1, y2 = hb2[z];
    float ca = 1.0f + 2.0f * xy + y2;
    float cb = 1.0f - x2;
    float rden = rcp_f(fmaxf(1.0f + 2.0f * xy + x2 * y2, 1e-15f));
    float o0 = (ca * r0 + cb * hv.x) * rden;
    float o1 = (ca * r1 + cb * hv.y) * rden;
    float o2 = (ca * r2 + cb * hv.z) * rden;
    float o3 = (ca * r3 + cb * hv.w) * rden;
    float no2 = wave_sum(o0 * o0 + o1 * o1 + o2 * o2 + o3 * o3);
    float nop = fmaxf(sqrtf(no2), 1e-15f);
    float s2 = (nop > MAXN) ? MAXN * rcp_f(nop) : 1.0f;
    float n2 = fminf(nop, MAXN);
    float fin = artanh_fast(n2) * rcp_f(n2) * s2;
    uint2 o; o.x = pk2(fin * o0, fin * o1); o.y = pk2(fin * o2, fin * o3);
    *(uint2*)(row + lane * 4) = o;
}

// wave-per-node CSR gather (packed (src,val)) + fused rowfuse2 chain -> bf16 out
__global__ void k_gather_fuse2(const int* __restrict__ rowptr, const uint2* __restrict__ padj,
                               const u16* __restrict__ xt, u16* __restrict__ out) {
    int z = blockIdx.y;
    rowptr += (size_t)z * (N_NODES + 1);
    padj += (size_t)z * NE;
    xt += (size_t)z * N_NODES * DH;
    out += (size_t)z * N_NODES * DH;
    int n = blockIdx.x * 4 + (threadIdx.x >> 6);
    int lane = threadIdx.x & 63;
    int beg = rowptr[n], end = rowptr[n + 1];
    float a0 = 0.f, a1 = 0.f, a2 = 0.f, a3 = 0.f;
    for (int i = beg; i < end; ++i) {
        uint2 p = padj[i];
        float v = __uint_as_float(p.y);
        uint2 u = *(const uint2*)(xt + (size_t)p.x * DH + lane * 4);
        a0 = fmaf(v, blo(u.x), a0);
        a1 = fmaf(v, bhi(u.x), a1);
        a2 = fmaf(v, blo(u.y), a2);
        a3 = fmaf(v, bhi(u.y), a3);
    }
    float ss = wave_sum(a0 * a0 + a1 * a1 + a2 * a2 + a3 * a3);
    float nraw = sqrtf(ss);
    float n_ = fmaxf(nraw, 1e-15f);
    float c1 = tanh_fast(n_) * rcp_f(n_);
    float nh = c1 * nraw;
    float np1 = fmaxf(nh, 1e-15f);
    float s1 = (np1 > MAXN) ? MAXN * rcp_f(np1) : 1.0f;
    float n1 = fminf(np1, MAXN);
    float cu = artanh_fast(n1) * rcp_f(n1) * s1 * c1;
    float u0 = fmaxf(cu * a0, 0.f), u1 = fmaxf(cu * a1, 0.f);
    float u2 = fmaxf(cu * a2, 0.f), u3 = fmaxf(cu * a3, 0.f);
    float ss2 = wave_sum(u0 * u0 + u1 * u1 + u2 * u2 + u3 * u3);
    float n2raw = sqrtf(ss2);
    float n2 = fmaxf(n2raw, 1e-15f);
    float c3 = tanh_fast(n2) * rcp_f(n2);
    float ne = c3 * n2raw;
    float np3 = fmaxf(ne, 1e-15f);
    float s3 = (np3 > MAXN) ? MAXN * rcp_f(np3) : 1.0f;
    float n3 = fminf(np3, MAXN);
    float cf = artanh_fast(n3) * rcp_f(n3) * s3 * c3;
    uint2 o; o.x = pk2(cf * u0, cf * u1); o.y = pk2(cf * u2, cf * u3);
    *(uint2*)(out + (size_t)n * DH + lane * 4) = o;
}

// wave-per-node: out[n] = d[n] + sum_in d[src]; bf16 in/out
__global__ void k_gather_add(const int* __restrict__ rowptr, const int* __restrict__ psrc,
                             const u16* __restrict__ d, u16* __restrict__ out) {
    int z = blockIdx.y;
    rowptr += (size_t)z * (N_NODES + 1);
    psrc += (size_t)z * NE;
    d += (size_t)z * N_NODES * DH;
    out += (size_t)z * N_NODES * DH;
    int n = blockIdx.x * 4 + (threadIdx.x >> 6);
    int lane = threadIdx.x & 63;
    int beg = rowptr[n], end = rowptr[n + 1];
    uint2 u0v = *(const uint2*)(d + (size_t)n * DH + lane * 4);
    float a0 = blo(u0v.x), a1 = bhi(u0v.x), a2 = blo(u0v.y), a3 = bhi(u0v.y);
    for (int i = beg; i < end; ++i) {
        int s = psrc[i];
        uint2 u = *(const uint2*)(d + (size_t)s * DH + lane * 4);
        a0 += blo(u.x); a1 += bhi(u.x); a2 += blo(u.y); a3 += bhi(u.y);
    }
    uint2 o; o.x = pk2(a0, a1); o.y = pk2(a2, a3);
    *(uint2*)(out + (size_t)n * DH + lane * 4) = o;
}

// batched column stats from bf16
__global__ void k_colstats(const u16* __restrict__ zp,
                           float* __restrict__ csum, float* __restrict__ csq) {
    int z = blockIdx.y;
    zp += (size_t)z * N_NODES * DH;
    csum += (size_t)z * DH;
    csq += (size_t)z * DH;
    int t = threadIdx.x;
    int r0 = blockIdx.x * 100;
    float s = 0.0f, q = 0.0f;
    for (int r = r0; r < r0 + 100; ++r) {
        float v = b2f(zp[(size_t)r * DH + t]);
        s += v;
        q += v * v;
    }
    atomicAdd(&csum[t], s);
    atomicAdd(&csq[t], q);
}

// grid-stride uint2 batchnorm + tanh, in-place bf16 (total4 = G*N*DH/4)
__global__ void k_normtanh_v(u16* __restrict__ zp, const float* __restrict__ csum,
                             const float* __restrict__ csq, const float* __restrict__ gamma,
                             const float* __restrict__ beta, int total4) {
    const float inv_n = 1.0f / N_NODES;
    int i = blockIdx.x * 256 + threadIdx.x;
    int stride = gridDim.x * 256;
    for (; i < total4; i += stride) {
        int e0 = i * 4;
        int z = e0 / (N_NODES * DH);
        int j0 = e0 & (DH - 1);
        int zb = z * DH + j0;
        uint2 u = ((uint2*)zp)[i];
        float v[4] = {blo(u.x), bhi(u.x), blo(u.y), bhi(u.y)};
        #pragma unroll
        for (int k = 0; k < 4; ++k) {
            float mu = csum[zb + k] * inv_n;
            float var = csq[zb + k] * inv_n - mu * mu;
            float inv = __builtin_amdgcn_rsqf(var + 1e-5f);
            v[k] = tanh_fast((v[k] - mu) * inv * gamma[zb + k] + beta[zb + k]);
        }
        uint2 o; o.x = pk2(v[0], v[1]); o.y = pk2(v[2], v[3]);
        ((uint2*)zp)[i] = o;
    }
}

// f1 slice of S,P (cols 0..511): thread t -> 2 cols via float2, packed u32 store
__global__ void k_pair0(const int* __restrict__ ei, const int* __restrict__ eid,
                        const float* __restrict__ f1, u16* __restrict__ S,
                        u16* __restrict__ P) {
    int b = blockIdx.x, t = threadIdx.x;
    int e = eid[b];
    int n0 = ei[e], n1 = ei[NE2 + e];
    float2 a = *(const float2*)(f1 + (size_t)n0 * D_INN + t * 2);
    float2 c = *(const float2*)(f1 + (size_t)n1 * D_INN + t * 2);
    ((unsigned int*)(S + (size_t)b * H3))[t] = pk2(a.x + c.x, a.y + c.y);
    ((unsigned int*)(P + (size_t)b * H3))[t] = pk2(a.x * c.x, a.y * c.y);
}

// batched channel slice of S,P from z_ch; 4 edges/block, uint2 lanes
__global__ void k_gather_ch(const int* __restrict__ ei, const int* __restrict__ eid,
                            const u16* __restrict__ zch, u16* __restrict__ S,
                            u16* __restrict__ P, int col0base) {
    int z = blockIdx.y;
    const u16* zp = zch + (size_t)z * N_NODES * DH;
    int col0 = col0base + z * DH;
    int b = blockIdx.x * 4 + (threadIdx.x >> 6);
    int lane = threadIdx.x & 63;
    int e = eid[b];
    int n0 = ei[e], n1 = ei[NE2 + e];
    uint2 ua = *(const uint2*)(zp + (size_t)n0 * DH + lane * 4);
    uint2 ub = *(const uint2*)(zp + (size_t)n1 * DH + lane * 4);
    float a0 = blo(ua.x), a1 = bhi(ua.x), a2 = blo(ua.y), a3 = bhi(ua.y);
    float c0 = blo(ub.x), c1 = bhi(ub.x), c2 = blo(ub.y), c3 = bhi(ub.y);
    uint2 so; so.x = pk2(a0 + c0, a1 + c1); so.y = pk2(a2 + c2, a3 + c3);
    uint2 po; po.x = pk2(a0 * c0, a1 * c1); po.y = pk2(a2 * c2, a3 * c3);
    *(uint2*)(S + (size_t)b * H3 + col0 + lane * 4) = so;
    *(uint2*)(P + (size_t)b * H3 + col0 + lane * 4) = po;
}

__global__ void k_final(const float* __restrict__ h2, const float* __restrict__ Wf3,
                        const float* __restrict__ bf3, float* __restrict__ out) {
    int r = blockIdx.x, t = threadIdx.x;
    const float* hr = h2 + (size_t)r * 576;
    float acc[7] = {0, 0, 0, 0, 0, 0, 0};
    for (int cb = t; cb < 576; cb += 64) {
        float h = hr[cb];
        #pragma unroll
        for (int o = 0; o < 7; ++o) acc[o] = fmaf(h, Wf3[o * 576 + cb], acc[o]);
    }
    #pragma unroll
    for (int o = 0; o < 7; ++o) {
        #pragma unroll
        for (int off = 32; off > 0; off >>= 1) acc[o] += __shfl_down(acc[o], off, 64);
    }
    if (t == 0) {
        #pragma unroll
        for (int o = 0; o < 7; ++o) out[(size_t)r * 7 + o] = acc[o] + bf3[o];
    }
}

// ===== bf16 MFMA GEMM (batched over blockIdx.z with strides).
// global_load_lds width-16 staging, coalesced: per 16-row group, LDS is
// row-major [16r][4 chunks x 16B] with chunk physically at p = c ^ ((r>>1)&3).
// Lane l (r=l>>2, p=l&3) fetches global chunk c = p ^ ((l>>3)&3) -> 64B/row
// contiguous source segments; LDS dest linear (wave base + lane*16).
// Fragment ds_read_b128 at r*64 + (q^((r>>1)&3))*16 -> 2-way bank alias (free).
// XCD-aware bijective block swizzle per z-slice (m204).
// EP: 2=sigmoid->bf16, 3=relu->bf16, 4=aux*relu->bf16, 5=bf16, 6=relu->f32,
//     7=bf16 with bias + (1+indeg[row])*cvec[col]  (rpe = edge rowptr base)
template <int EP>
__global__ __launch_bounds__(256, 2) void k_gemm_mfma(
    const u16* __restrict__ A, const u16* __restrict__ W,
    const float* __restrict__ bias, void* __restrict__ outv,
    const u16* __restrict__ aux, const int* __restrict__ rpe,
    const float* __restrict__ cvec, int M, int N, int K,
    size_t sA, size_t sW, size_t sC, int sBias) {
    __shared__ short As[4096];   // 8 groups x 1KB
    __shared__ short Ws[4096];
    const int z = blockIdx.z;
    A += (size_t)z * sA;
    W += (size_t)z * sW;
    const size_t zC = (size_t)z * sC;
    const int* rp = (EP == 7) ? rpe + (size_t)z * (N_NODES + 1) : nullptr;
    const float* cv = (EP == 7) ? cvec + (size_t)z * DH : nullptr;
    // XCD bijective swizzle within this z-slice
    const int gx = gridDim.x;
    const int nwg = gx * gridDim.y;
    const int orig = blockIdx.y * gx + blockIdx.x;
    const int q8 = nwg >> 3, r8 = nwg & 7, xcd = orig & 7;
    const int wg = (xcd < r8 ? xcd * (q8 + 1) : r8 * (q8 + 1) + (xcd - r8) * q8) + (orig >> 3);
    const int row0 = (wg / gx) * 128, col0 = (wg % gx) * 128;
    const int t = threadIdx.x;
    const int lane = t & 63;
    const int w = t >> 6;
    const int wr = w >> 1, wc = w & 1;
    // staging source coords: lane l -> row-in-group l>>2, global chunk (l&3)^((l>>3)&3)
    const int sr = lane >> 2;
    const int csrc = (lane & 3) ^ ((lane >> 3) & 3);
    int gr[2], gc[2];
    #pragma unroll
    for (int p = 0; p < 2; ++p) {
        int g = w + p * 4;
        gr[p] = row0 + g * 16 + sr; if (gr[p] >= M) gr[p] = M - 1;
        gc[p] = col0 + g * 16 + sr; if (gc[p] >= N) gc[p] = N - 1;
    }
    // fragment read offset (shorts): row fr, chunk q -> fr*32 + (q^((fr>>1)&3))*8
    const int fr = lane & 15, fq = lane >> 4;
    const int rdoff = fr * 32 + ((fq ^ ((fr >> 1) & 3)) * 8);
    f32x4 acc[4][4] = {};
    for (int k0 = 0; k0 < K; k0 += 32) {
        #pragma unroll
        for (int p = 0; p < 2; ++p) {
            int g = w + p * 4;
            __builtin_amdgcn_global_load_lds(
                (const __attribute__((address_space(1))) unsigned int*)(A + (size_t)gr[p] * K + k0 + csrc * 8),
                (__attribute__((address_space(3))) unsigned int*)(As + g * 512), 16, 0, 0);
            __builtin_amdgcn_global_load_lds(
                (const __attribute__((address_space(1))) unsigned int*)(W + (size_t)gc[p] * K + k0 + csrc * 8),
                (__attribute__((address_space(3))) unsigned int*)(Ws + g * 512), 16, 0, 0);
        }
        __syncthreads();
        bf16x8 af[4], bfr[4];
        #pragma unroll
        for (int m = 0; m < 4; ++m)
            af[m] = *(const bf16x8*)(As + (wr * 4 + m) * 512 + rdoff);
        #pragma unroll
        for (int n = 0; n < 4; ++n)
            bfr[n] = *(const bf16x8*)(Ws + (wc * 4 + n) * 512 + rdoff);
        #pragma unroll
        for (int m = 0; m < 4; ++m)
            #pragma unroll
            for (int n = 0; n < 4; ++n)
                acc[m][n] = __builtin_amdgcn_mfma_f32_16x16x32_bf16(af[m], bfr[n], acc[m][n], 0, 0, 0);
        __syncthreads();
    }
    const int cl = lane & 15, rh = (lane >> 4) * 4;
    #pragma unroll
    for (int m = 0; m < 4; ++m) {
        float indf[4];
        if (EP == 7) {
            #pragma unroll
            for (int r = 0; r < 4; ++r) {
                int row = row0 + wr * 64 + m * 16 + rh + r;
                if (row >= M) row = M - 1;
                indf[r] = 1.0f + (float)(rp[row + 1] - rp[row]);
            }
        }
        #pragma unroll
        for (int n = 0; n < 4; ++n) {
            int col = col0 + wc * 64 + n * 16 + cl;
            if (col >= N) continue;
            float bv = bias ? bias[z * sBias + col] : 0.0f;
            float cvc = (EP == 7) ? cv[col] : 0.0f;
            #pragma unroll
            for (int r = 0; r < 4; ++r) {
                int row = row0 + wr * 64 + m * 16 + rh + r;
                if (row >= M) continue;
                float v = acc[m][n][r] + bv;
                size_t idx = zC + (size_t)row * N + col;
                if (EP == 2) ((u16*)outv)[idx] = f2b(sigmoid_fast(v));
                if (EP == 3) ((u16*)outv)[idx] = f2b(fmaxf(v, 0.0f));
                if (EP == 4) { float g = b2f(aux[idx]); ((u16*)outv)[idx] = f2b(g * fmaxf(v, 0.0f)); }
                if (EP == 5) ((u16*)outv)[idx] = f2b(v);
                if (EP == 6) ((float*)outv)[idx] = fmaxf(v, 0.0f);
                if (EP == 7) ((u16*)outv)[idx] = f2b(v + indf[r] * cvc);
            }
        }
    }
}

static inline void gemm_b(int ep, const u16* A, const u16* W, const float* bias, void* out,
                          const u16* aux, const int* rpe, const float* cvec,
                          int M, int N, int K, int Z,
                          size_t sA, size_t sW, size_t sC, int sBias, hipStream_t st) {
    dim3 g((N + 127) / 128, (M + 127) / 128, Z);
    switch (ep) {
        case 2: k_gemm_mfma<2><<<g, 256, 0, st>>>(A, W, bias, out, aux, rpe, cvec, M, N, K, sA, sW, sC, sBias); break;
        case 3: k_gemm_mfma<3><<<g, 256, 0, st>>>(A, W, bias, out, aux, rpe, cvec, M, N, K, sA, sW, sC, sBias); break;
        case 4: k_gemm_mfma<4><<<g, 256, 0, st>>>(A, W, bias, out, aux, rpe, cvec, M, N, K, sA, sW, sC, sBias); break;
        case 5: k_gemm_mfma<5><<<g, 256, 0, st>>>(A, W, bias, out, aux, rpe, cvec, M, N, K, sA, sW, sC, sBias); break;
        case 6: k_gemm_mfma<6><<<g, 256, 0, st>>>(A, W, bias, out, aux, rpe, cvec, M, N, K, sA, sW, sC, sBias); break;
        case 7: k_gemm_mfma<7><<<g, 256, 0, st>>>(A, W, bias, out, aux, rpe, cvec, M, N, K, sA, sW, sC, sBias); break;
    }
}

static inline void conv_w(const float* s, u16* d, size_t n, hipStream_t st) {
    int n4 = (int)(n / 4);
    int grid = (n4 + 255) / 256;
    if (grid > 2048) grid = 2048;
    k_f2b<<<grid, 256, 0, st>>>(s, d, n4);
}

extern "C" void kernel_launch(void* const* d_in, const int* in_sizes, int n_in, void* d_out,
                              int out_size, void* d_ws, size_t ws_size, hipStream_t stream) {
    const float* f1 = (const float*)d_in[0];
    const int* adj_src = (const int*)d_in[1];
    const int* adj_dst = (const int*)d_in[2];
    const float* adj_val = (const float*)d_in[3];
    const int* edge_src = (const int*)d_in[4];
    const int* edge_dst = (const int*)d_in[5];
    const int* edge_index = (const int*)d_in[6];
    const int* edge_id = (const int*)d_in[7];
    const float* W_hyp = (const float*)d_in[8];
    const float* b_hyp = (const float*)d_in[9];
    const float* Wd = (const float*)d_in[10];
    const float* bd = (const float*)d_in[11];
    const float* Wg1 = (const float*)d_in[12];
    const float* bg1 = (const float*)d_in[13];
    const float* gamma = (const float*)d_in[14];
    const float* beta = (const float*)d_in[15];
    const float* Wg2 = (const float*)d_in[16];
    const float* bg2 = (const float*)d_in[17];
    const float* Wgate = (const float*)d_in[18];
    const float* bgate = (const float*)d_in[19];
    const float* Wint = (const float*)d_in[20];
    const float* bint = (const float*)d_in[21];
    const float* Wout = (const float*)d_in[22];
    const float* bout = (const float*)d_in[23];
    const float* Wf1 = (const float*)d_in[24];
    const float* bf1 = (const float*)d_in[25];
    const float* Wf2 = (const float*)d_in[26];
    const float* bf2 = (const float*)d_in[27];
    const float* Wf3 = (const float*)d_in[28];
    const float* bf3 = (const float*)d_in[29];
    float* outp = (float*)d_out;

    // ---- workspace bump allocator (~240 MB) ----
    char* base = (char*)d_ws;
    size_t off = 0;
    auto alloc = [&](size_t bytes) -> char* {
        char* p = base + off;
        off += (bytes + 255) & ~(size_t)255;
        return p;
    };
    u16* Whyp_b = (u16*)alloc((size_t)NCH * DH * D_INN * 2);
    u16* Wdt_b  = (u16*)alloc((size_t)NCH * DH * DH * 2);   // Wd^T bf16
    u16* Wc_b   = (u16*)alloc((size_t)NCH * DH * DH * 2);   // Wg1 @ Wd
    u16* Wg1_b  = (u16*)alloc((size_t)NCH * DH * DH * 2);
    u16* Wg2_b  = (u16*)alloc((size_t)NCH * DH * DH * 2);
    u16* Wgate_b = (u16*)alloc((size_t)H3 * H3 * 2);
    u16* Wint_b  = (u16*)alloc((size_t)H3 * H3 * 2);
    u16* Wout_b  = (u16*)alloc((size_t)H3 * H3 * 2);
    u16* Wf1_b   = (u16*)alloc((size_t)1152 * H3 * 2);
    u16* Wf2_b   = (u16*)alloc((size_t)576 * 1152 * 2);
    u16* S_b = (u16*)alloc((size_t)NB * H3 * 2);
    u16* P_b = (u16*)alloc((size_t)NB * H3 * 2);
    const size_t NDB = (size_t)N_NODES * DH;       // per-channel elems
    u16* buf1 = (u16*)alloc(4 * NDB * 2);          // group ping
    u16* buf2 = (u16*)alloc(4 * NDB * 2);          // group pong
    u16* xhyp_b = (u16*)alloc((size_t)N_NODES * D_INN * 2);
    // merged CSR scratch (2G slices; G<=4): adj slices [0,G), edge slices [G,2G)
    int* cntC = (int*)alloc(8 * (size_t)N_NODES * 4);        // doubles as cursor
    int* rowptrC = (int*)alloc(8 * (size_t)(N_NODES + 1) * 4);
    uint2* padjC = (uint2*)alloc(4 * (size_t)NE * 8);        // packed (src,val)
    int* psrcE = (int*)alloc(4 * (size_t)NE * 4);
    float* xhn = (float*)alloc((size_t)N_NODES * 4);
    float* hb = (float*)alloc((size_t)NCH * DH * 4);
    float* hb2 = (float*)alloc(NCH * 4);
    float* csum = (float*)alloc((size_t)4 * DH * 4);
    float* csq = (float*)alloc((size_t)4 * DH * 4);
    float* cvec_d = (float*)alloc((size_t)NCH * DH * 4);
    // stage-C overlays (GNN buffers dead by then)
    u16* G_b = buf1;                 // 37.75 MB <= 40.96
    float* h2f = (float*)buf2;       // 18.87 MB <= 40.96

    const int EG = (NE + 255) / 256;

    conv_w(W_hyp, Whyp_b, (size_t)NCH * DH * D_INN, stream);
    conv_w(Wg1, Wg1_b, (size_t)NCH * DH * DH, stream);
    conv_w(Wg2, Wg2_b, (size_t)NCH * DH * DH, stream);
    conv_w(Wgate, Wgate_b, (size_t)H3 * H3, stream);
    conv_w(Wint, Wint_b, (size_t)H3 * H3, stream);
    conv_w(Wout, Wout_b, (size_t)H3 * H3, stream);
    conv_w(Wf1, Wf1_b, (size_t)1152 * H3, stream);
    conv_w(Wf2, Wf2_b, (size_t)576 * 1152, stream);
    // Wc = Wg1 @ Wd (via Wd^T), cvec = Wg1 @ bd
    k_twd<<<dim3(16, 16, NCH), 256, 0, stream>>>(Wd, Wdt_b);
    gemm_b(5, Wg1_b, Wdt_b, nullptr, Wc_b, nullptr, nullptr, nullptr,
           DH, DH, DH, NCH, (size_t)DH * DH, (size_t)DH * DH, (size_t)DH * DH, 0, stream);
    k_cvec<<<NCH, 256, 0, stream>>>(Wg1, bd, cvec_d);

    k_expmap_proj_in<<<N_NODES, 256, 0, stream>>>(f1, xhyp_b, xhn);
    k_hb<<<NCH, 256, 0, stream>>>(b_hyp, hb, hb2);
    k_pair0<<<NB, 256, 0, stream>>>(edge_index, edge_id, f1, S_b, P_b);

    const int g0s[2] = {0, 4};
    const int gns[2] = {4, 3};
    for (int gi = 0; gi < 2; ++gi) {
        const int g0 = g0s[gi], G = gns[gi];
        const size_t eoff = (size_t)g0 * NE;
        const int G2 = 2 * G;
        const int* rpE = rowptrC + (size_t)G * (N_NODES + 1);
        // --- merged CSR build (both graphs, one launch set) ---
        k_izero<<<(G2 * N_NODES + 255) / 256, 256, 0, stream>>>(cntC, G2 * N_NODES);
        k_hist2<<<dim3(EG, G2), 256, 0, stream>>>(adj_dst + eoff, edge_dst + eoff, cntC, G);
        k_scan<<<G2, 256, 0, stream>>>(cntC, rowptrC);
        k_place2<<<dim3(EG, G2), 256, 0, stream>>>(adj_src + eoff, adj_dst + eoff,
                                                   adj_val + eoff, edge_src + eoff,
                                                   edge_dst + eoff, cntC, padjC, psrcE, G);
        // --- batched pipeline ---
        gemm_b(5, xhyp_b, Whyp_b + (size_t)g0 * DH * D_INN, nullptr, buf1, nullptr,
               nullptr, nullptr, N_NODES, DH, D_INN, G, 0, (size_t)DH * D_INN, NDB, 0, stream);
        k_rowfuse1<<<dim3(N_NODES / 4, G), 256, 0, stream>>>(buf1, xhn, hb + g0 * DH, hb2 + g0);
        k_gather_fuse2<<<dim3(N_NODES / 4, G), 256, 0, stream>>>(rowptrC, padjC, buf1, buf2);
        // ug = (I + S_e) u
        k_gather_add<<<dim3(N_NODES / 4, G), 256, 0, stream>>>(rpE, psrcE, buf2, buf1);
        // z = ug @ Wc^T + (1+indeg)*cvec + bg1   (Wd GEMM fused away)
        gemm_b(7, buf1, Wc_b + (size_t)g0 * DH * DH, bg1 + g0 * DH, buf2, nullptr,
               rpE, cvec_d + (size_t)g0 * DH, N_NODES, DH, DH, G,
               NDB, (size_t)DH * DH, NDB, DH, stream);
        k_zero<<<(G * DH + 255) / 256, 256, 0, stream>>>(csum, G * DH);
        k_zero<<<(G * DH + 255) / 256, 256, 0, stream>>>(csq, G * DH);
        k_colstats<<<dim3(200, G), 256, 0, stream>>>(buf2, csum, csq);
        {
            int total4 = (int)(G * NDB / 4);
            int blocks = (total4 + 255) / 256;
            if (blocks > 2048) blocks = 2048;
            k_normtanh_v<<<blocks, 256, 0, stream>>>(buf2, csum, csq, gamma + g0 * DH,
                                                     beta + g0 * DH, total4);
        }
        gemm_b(5, buf2, Wg2_b + (size_t)g0 * DH * DH, bg2 + g0 * DH, buf1, nullptr,
               nullptr, nullptr, N_NODES, DH, DH, G, NDB, (size_t)DH * DH, NDB, DH, stream);
        k_gather_ch<<<dim3(NB / 4, G), 256, 0, stream>>>(edge_index, edge_id, buf1, S_b, P_b,
                                                         D_INN + g0 * DH);
    }

    // stage C (bf16 MFMA; gate->G_b, gi->S_b, g->P_b, h1->G_b, h2->h2f)
    gemm_b(2, S_b, Wgate_b, bgate, G_b, nullptr, nullptr, nullptr, NB, H3, H3, 1, 0, 0, 0, 0, stream);
    gemm_b(4, P_b, Wint_b, bint, S_b, G_b, nullptr, nullptr, NB, H3, H3, 1, 0, 0, 0, 0, stream);
    gemm_b(5, S_b, Wout_b, bout, P_b, nullptr, nullptr, nullptr, NB, H3, H3, 1, 0, 0, 0, 0, stream);
    gemm_b(3, P_b, Wf1_b, bf1, G_b, nullptr, nullptr, nullptr, NB, 1152, H3, 1, 0, 0, 0, 0, stream);
    gemm_b(6, G_b, Wf2_b, bf2, h2f, nullptr, nullptr, nullptr, NB, 576, 1152, 1, 0, 0, 0, 0, stream);
    k_final<<<NB, 64, 0, stream>>>(h2f, Wf3, bf3, outp);
}